// Round 6
// baseline (564.968 us; speedup 1.0000x reference)
//
#include <hip/hip_runtime.h>
#include <hip/hip_bf16.h>
#include <stdint.h>

// ---------------------------------------------------------------------------
// GNNEncoder: 3 x (GCNConv -> BatchNorm1d(train) -> ELU)
// N=50000, E=1.6M, dims 128->128->128->64
//
// R6: L2-resident sliced aggregation with high MLP.
//   h,y stored slice-major [S][n][32cols]; slice = blockIdx & (S-1) so each
//   slice (3.2MB) pins into one XCD-pair's L2 (R3's locality) while keeping
//   R4's unroll-16 load-then-FMA wave structure (16 edges in flight):
//   4 edge-groups x 16 lanes, xor-shuffle reduce at the end.
//   CSR build: R5 two-level counting sort (kept).
// ---------------------------------------------------------------------------

#define NCH 256   // edge chunks (partition blocks)

static __device__ __forceinline__ float bflo(uint32_t u) {
    union { uint32_t u; float f; } x; x.u = u << 16; return x.f;
}
static __device__ __forceinline__ float bfhi(uint32_t u) {
    union { uint32_t u; float f; } x; x.u = u & 0xffff0000u; return x.f;
}
static __device__ __forceinline__ uint16_t f2bf(float f) {
    union { float f; uint32_t u; } x; x.f = f;
    uint32_t r = x.u + 0x7fffu + ((x.u >> 16) & 1u);   // RNE
    return (uint16_t)(r >> 16);
}
static __device__ __forceinline__ float eluf(float v) {
    return v > 0.f ? v : expm1f(v);
}

// --------------------------------------------- P1: coarse histogram
__global__ __launch_bounds__(1024) void hist_coarse_kernel(
    const int* __restrict__ dst, uint32_t* __restrict__ coarse,
    int E, int EPC, int NBUK) {
    __shared__ uint32_t cnt[256];
    int b = blockIdx.x, t = threadIdx.x;
    if (t < 256) cnt[t] = 0;
    __syncthreads();
    int e0 = b * EPC, e1 = min(E, e0 + EPC);
    for (int e = e0 + t; e < e1; e += 1024) atomicAdd(&cnt[dst[e] >> 8], 1u);
    __syncthreads();
    if (t < NBUK) coarse[(size_t)t * NCH + b] = cnt[t];
}

// --------------------------------------------- P2: base scan (1 block)
__global__ __launch_bounds__(1024) void basescan_kernel(
    uint32_t* __restrict__ coarse, int* __restrict__ beb,
    int* __restrict__ row_start, int NBUK, int E, int n) {
    __shared__ int btot[256];
    __shared__ int wt[4];
    int t = threadIdx.x;
    int sum = 0;
    if (t < NBUK) {
        uint32_t* rowp = coarse + (size_t)t * NCH;
        uint32_t run = 0;
        for (int ch = 0; ch < NCH; ++ch) {
            uint32_t v = rowp[ch];
            rowp[ch] = run;
            run += v;
        }
        sum = (int)run;
    }
    if (t < 256) btot[t] = (t < NBUK) ? sum : 0;
    __syncthreads();
    int x = 0, v = 0;
    if (t < 256) {
        int lane = t & 63, w = t >> 6;
        v = btot[t];
        x = v;
        #pragma unroll
        for (int off = 1; off < 64; off <<= 1) {
            int m = __shfl_up(x, off);
            if (lane >= off) x += m;
        }
        if (lane == 63) wt[w] = x;
    }
    __syncthreads();
    if (t < 256) {
        int w = t >> 6, woff = 0;
        for (int j = 0; j < w; ++j) woff += wt[j];
        int excl = woff + x - v;
        if (t < NBUK) beb[t] = excl;
    }
    if (t == 0) {
        beb[NBUK] = E;
        row_start[n] = E;
    }
}

// --------------------------------------------- P3: partition into buckets
__global__ __launch_bounds__(1024) void partition_kernel(
    const int* __restrict__ src, const int* __restrict__ dst,
    const uint32_t* __restrict__ coarse, const int* __restrict__ beb,
    uint32_t* __restrict__ rec, int E, int EPC, int NBUK) {
    __shared__ int cur[256];
    int b = blockIdx.x, t = threadIdx.x;
    if (t < NBUK) cur[t] = (int)coarse[(size_t)t * NCH + b] + beb[t];
    __syncthreads();
    int e0 = b * EPC, e1 = min(E, e0 + EPC);
    for (int e = e0 + t; e < e1; e += 1024) {
        int d = dst[e];
        int pos = atomicAdd(&cur[d >> 8], 1);
        rec[pos] = (uint32_t)src[e] | ((uint32_t)(d & 255) << 16);
    }
}

// --------------------------------------------- P4: fine placement per bucket
__global__ __launch_bounds__(1024) void fine_kernel(
    const uint32_t* __restrict__ rec, const int* __restrict__ beb,
    int* __restrict__ row_start, float* __restrict__ dis,
    int* __restrict__ csr_src, int n) {
    __shared__ int cnt[256];
    __shared__ int wt[4];
    int b = blockIdx.x, t = threadIdx.x;
    int e0 = beb[b], e1 = beb[b + 1];
    if (t < 256) cnt[t] = 0;
    __syncthreads();
    for (int i = e0 + t; i < e1; i += 1024)
        atomicAdd(&cnt[(rec[i] >> 16) & 255], 1);
    __syncthreads();
    int x = 0, deg = 0;
    if (t < 256) {
        int lane = t & 63, w = t >> 6;
        deg = cnt[t];
        x = deg;
        #pragma unroll
        for (int off = 1; off < 64; off <<= 1) {
            int m = __shfl_up(x, off);
            if (lane >= off) x += m;
        }
        if (lane == 63) wt[w] = x;
    }
    __syncthreads();
    int excl = 0;
    if (t < 256) {
        int w = t >> 6, woff = 0;
        for (int j = 0; j < w; ++j) woff += wt[j];
        excl = woff + x - deg;
        int node = (b << 8) + t;
        if (node < n) {
            row_start[node] = e0 + excl;
            dis[node] = rsqrtf(1.0f + (float)deg);
        }
    }
    __syncthreads();
    if (t < 256) cnt[t] = e0 + excl;
    __syncthreads();
    for (int i = e0 + t; i < e1; i += 1024) {
        uint32_t r = rec[i];
        int pos = atomicAdd(&cnt[(r >> 16) & 255], 1);
        csr_src[pos] = (int)(r & 0xffffu);
    }
}

// ------------------------------------------------------------------- GEMM
// h (bf16, slice-major [F/32][n][32]) = act(in)[n][128] @ W[128][F]
// in: row-major [n][128] (layer 0) or slice-major [4][n][32] (layers 1,2).
template <int F, bool BN, bool SLICED_IN>
__global__ __launch_bounds__(512) void gemm_kernel(
    const float* __restrict__ in, const float* __restrict__ W,
    const float* __restrict__ sc, const float* __restrict__ sh,
    uint16_t* __restrict__ h, int n) {
    constexpr int K = 128;
    constexpr int BM = 128;
    __shared__ float xs[K][BM + 4];   // transposed: xs[k][r]
    __shared__ float ws[K][F];
    int t = threadIdx.x;
    int row0 = blockIdx.x * BM;

    for (int i = t * 4; i < K * F; i += 512 * 4) {
        *(float4*)((float*)ws + i) = *(const float4*)(W + i);
    }
    for (int idx = t; idx < BM * K / 4; idx += 512) {
        int r = idx >> 5;
        int k4 = (idx & 31) << 2;
        int gr = row0 + r;
        float4 v = make_float4(0.f, 0.f, 0.f, 0.f);
        if (gr < n) {
            const float* p;
            if (SLICED_IN)
                p = in + ((size_t)(k4 >> 5) * n + gr) * 32 + (k4 & 31);
            else
                p = in + (size_t)gr * K + k4;
            v = *(const float4*)p;
        }
        if (BN) {
            float4 s4 = *(const float4*)(sc + k4);
            float4 h4 = *(const float4*)(sh + k4);
            v.x = eluf(v.x * s4.x + h4.x);
            v.y = eluf(v.y * s4.y + h4.y);
            v.z = eluf(v.z * s4.z + h4.z);
            v.w = eluf(v.w * s4.w + h4.w);
        }
        xs[k4 + 0][r] = v.x;
        xs[k4 + 1][r] = v.y;
        xs[k4 + 2][r] = v.z;
        xs[k4 + 3][r] = v.w;
    }
    __syncthreads();

    constexpr int CW = F / 16;
    int tx = t & 15;
    int ty = t >> 4;
    float acc[4][CW];
    #pragma unroll
    for (int r = 0; r < 4; ++r)
        #pragma unroll
        for (int c = 0; c < CW; ++c) acc[r][c] = 0.f;

    for (int k = 0; k < K; ++k) {
        float4 xv = *(const float4*)&xs[k][ty * 4];
        float wv[CW];
        *(float4*)wv = *(const float4*)&ws[k][tx * CW];
        if (CW == 8) *(float4*)(wv + 4) = *(const float4*)&ws[k][tx * CW + 4];
        const float* xp = &xv.x;
        #pragma unroll
        for (int r = 0; r < 4; ++r)
            #pragma unroll
            for (int c = 0; c < CW; ++c)
                acc[r][c] = fmaf(xp[r], wv[c], acc[r][c]);
    }

    int col0 = tx * CW;
    int sl = col0 >> 5, off = col0 & 31;
    #pragma unroll
    for (int r = 0; r < 4; ++r) {
        int row = row0 + ty * 4 + r;
        if (row < n) {
            uint16_t* dstp = h + ((size_t)sl * n + row) * 32 + off;
            uint32_t p[CW / 2];
            #pragma unroll
            for (int c = 0; c < CW; c += 2)
                p[c / 2] = (uint32_t)f2bf(acc[r][c]) | ((uint32_t)f2bf(acc[r][c + 1]) << 16);
            if (CW == 8) *(uint4*)dstp = make_uint4(p[0], p[1], p[2], p[3]);
            else         *(uint2*)dstp = make_uint2(p[0], p[1]);
        }
    }
}

// -------------------------------------------------------------------- AGG
// Slice-major: h [S][n][16 u32], y [S][n][32 f32]; slice = bid & (S-1)
// (consecutive blocks -> different XCDs, pinning each 3.2MB slice in L2).
// Wave = 1 node: 4 edge-groups x 16 lanes, unroll-4 (16 edges in flight),
// xor-shuffle reduce over groups at the end.
template <int S>
__global__ __launch_bounds__(256) void agg_sliced_kernel(
    const uint32_t* __restrict__ hp,
    const int* __restrict__ row_start, const int* __restrict__ csr_src,
    const float* __restrict__ dis, const float* __restrict__ bias,
    float* __restrict__ y, int n) {
    int bid = blockIdx.x;
    int sl = bid & (S - 1);
    int grp = bid / S;
    int wv = threadIdx.x >> 6;
    int lane = threadIdx.x & 63;
    int node = grp * 4 + wv;
    if (node >= n) return;
    int eg = lane >> 4, lig = lane & 15;
    int s = row_start[node], e = row_start[node + 1];
    float dd = dis[node];
    const uint32_t* hs = hp + (size_t)sl * n * 16;
    float a0 = 0.f, a1 = 0.f;
    int i = s;
    for (; i + 16 <= e; i += 16) {
        int sid[4];
        #pragma unroll
        for (int st = 0; st < 4; ++st) sid[st] = csr_src[i + st * 4 + eg];
        uint32_t u[4];
        #pragma unroll
        for (int st = 0; st < 4; ++st) u[st] = hs[(size_t)sid[st] * 16 + lig];
        float c[4];
        #pragma unroll
        for (int st = 0; st < 4; ++st) c[st] = dis[sid[st]] * dd;
        #pragma unroll
        for (int st = 0; st < 4; ++st) {
            a0 = fmaf(c[st], bflo(u[st]), a0);
            a1 = fmaf(c[st], bfhi(u[st]), a1);
        }
    }
    for (; i < e; i += 4) {
        int ei = i + eg;
        bool ok = ei < e;
        int sid = ok ? csr_src[ei] : node;
        uint32_t u = hs[(size_t)sid * 16 + lig];
        float c = ok ? dis[sid] * dd : 0.f;
        a0 = fmaf(c, bflo(u), a0);
        a1 = fmaf(c, bfhi(u), a1);
    }
    a0 += __shfl_xor(a0, 16); a1 += __shfl_xor(a1, 16);
    a0 += __shfl_xor(a0, 32); a1 += __shfl_xor(a1, 32);
    if (eg == 0) {
        uint32_t u = hs[(size_t)node * 16 + lig];
        float c2 = dd * dd;
        int col = sl * 32 + lig * 2;
        a0 = fmaf(c2, bflo(u), a0) + bias[col];
        a1 = fmaf(c2, bfhi(u), a1) + bias[col + 1];
        *(float2*)(y + ((size_t)sl * n + node) * 32 + lig * 2) = make_float2(a0, a1);
    }
}

// ------------------------------------------------------------ BN statistics
// y slice-major [S][n][32]; grid = (rowChunks, S)
__global__ __launch_bounds__(256) void colsum_kernel(
    const float* __restrict__ y, int n,
    float* __restrict__ sums, float* __restrict__ sumsq) {
    int sl = blockIdx.y;
    const float* ys = y + (size_t)sl * n * 32;
    int t = threadIdx.x, cg = t & 7, rt = t >> 3;   // 8 float4 groups, 32 rows
    float4 s = make_float4(0.f, 0.f, 0.f, 0.f);
    float4 q = make_float4(0.f, 0.f, 0.f, 0.f);
    for (int row = blockIdx.x * 32 + rt; row < n; row += gridDim.x * 32) {
        float4 v = *(const float4*)(ys + (size_t)row * 32 + cg * 4);
        s.x += v.x; s.y += v.y; s.z += v.z; s.w += v.w;
        q.x += v.x * v.x; q.y += v.y * v.y; q.z += v.z * v.z; q.w += v.w * v.w;
    }
    __shared__ float4 rs[32][8], rq[32][8];
    rs[rt][cg] = s; rq[rt][cg] = q;
    __syncthreads();
    for (int st = 16; st > 0; st >>= 1) {
        if (rt < st) {
            float4 o = rs[rt + st][cg], p = rq[rt + st][cg];
            rs[rt][cg].x += o.x; rs[rt][cg].y += o.y;
            rs[rt][cg].z += o.z; rs[rt][cg].w += o.w;
            rq[rt][cg].x += p.x; rq[rt][cg].y += p.y;
            rq[rt][cg].z += p.z; rq[rt][cg].w += p.w;
        }
        __syncthreads();
    }
    if (rt == 0) {
        float4 fs = rs[0][cg], fq = rq[0][cg];
        int col = sl * 32 + cg * 4;
        atomicAdd(&sums[col + 0], fs.x); atomicAdd(&sums[col + 1], fs.y);
        atomicAdd(&sums[col + 2], fs.z); atomicAdd(&sums[col + 3], fs.w);
        atomicAdd(&sumsq[col + 0], fq.x); atomicAdd(&sumsq[col + 1], fq.y);
        atomicAdd(&sumsq[col + 2], fq.z); atomicAdd(&sumsq[col + 3], fq.w);
    }
}

template <int F>
__global__ void finalize_kernel(const float* __restrict__ sums,
                                const float* __restrict__ sumsq,
                                const float* __restrict__ g, const float* __restrict__ be,
                                float* __restrict__ sc, float* __restrict__ sh, float n) {
    int c = threadIdx.x;
    if (c < F) {
        float m = sums[c] / n;
        float v = sumsq[c] / n - m * m;           // biased variance
        float r = rsqrtf(v + 1e-5f);
        float scale = r * g[c];
        sc[c] = scale;
        sh[c] = be[c] - m * scale;
    }
}

// ----------------------------------------------------------- final BN+ELU
// y slice-major [2][n][32] -> out row-major [n][64]
__global__ __launch_bounds__(256) void out_kernel(
    const float* __restrict__ y, const float* __restrict__ sc,
    const float* __restrict__ sh, float* __restrict__ out, int n) {
    int idx = blockIdx.x * 256 + threadIdx.x;
    if (idx >= n * 16) return;
    int node = idx >> 4, q = idx & 15;
    int sl = q >> 3, wq = (q & 7) * 4;
    int col = sl * 32 + wq;
    float4 v = *(const float4*)(y + ((size_t)sl * n + node) * 32 + wq);
    float4 s4 = *(const float4*)(sc + col);
    float4 h4 = *(const float4*)(sh + col);
    v.x = eluf(v.x * s4.x + h4.x);
    v.y = eluf(v.y * s4.y + h4.y);
    v.z = eluf(v.z * s4.z + h4.z);
    v.w = eluf(v.w * s4.w + h4.w);
    *(float4*)(out + (size_t)node * 64 + q * 4) = v;
}

// ---------------------------------------------------------------------------
extern "C" void kernel_launch(void* const* d_in, const int* in_sizes, int n_in,
                              void* d_out, int out_size, void* d_ws, size_t ws_size,
                              hipStream_t stream) {
    const float* x   = (const float*)d_in[0];
    const int*   edge = (const int*)d_in[1];
    const float* W0 = (const float*)d_in[2];
    const float* b0 = (const float*)d_in[3];
    const float* g0 = (const float*)d_in[4];
    const float* be0 = (const float*)d_in[5];
    const float* W1 = (const float*)d_in[6];
    const float* b1 = (const float*)d_in[7];
    const float* g1 = (const float*)d_in[8];
    const float* be1 = (const float*)d_in[9];
    const float* W2 = (const float*)d_in[10];
    const float* b2 = (const float*)d_in[11];
    const float* g2 = (const float*)d_in[12];
    const float* be2 = (const float*)d_in[13];

    const int n = in_sizes[0] / 128;     // 50000
    const int E = in_sizes[1] / 2;       // 1600000
    const int* esrc = edge;
    const int* edst = edge + E;

    const int NBUK = (n + 255) >> 8;               // 256-node buckets (<=256)
    const int EPC  = (E + NCH - 1) / NCH;          // edges per chunk

    char* w = (char*)d_ws;
    auto carve = [&](size_t bytes) -> void* {
        void* p = (void*)w;
        w += (bytes + 255) & ~(size_t)255;
        return p;
    };
    float*    y         = (float*)carve((size_t)n * 128 * 4);     // slice-major
    uint16_t* h         = (uint16_t*)carve((size_t)n * 128 * 2);  // slice-major
    int*      csr_src   = (int*)carve((size_t)E * 4);
    uint32_t* rec       = (uint32_t*)carve((size_t)E * 4);
    uint32_t* coarse    = (uint32_t*)carve((size_t)NBUK * NCH * 4);
    int*      beb       = (int*)carve((size_t)(NBUK + 1) * 4);
    int*      row_start = (int*)carve((size_t)(n + 1) * 4);
    float*    dis       = (float*)carve((size_t)n * 4);
    float*    sums      = (float*)carve(128 * 4);
    float*    sumsq     = (float*)carve(128 * 4);
    float*    sc        = (float*)carve(128 * 4);
    float*    sh        = (float*)carve(128 * 4);

    // ---- CSR build: two-level counting sort
    hist_coarse_kernel<<<NCH, 1024, 0, stream>>>(edst, coarse, E, EPC, NBUK);
    basescan_kernel<<<1, 1024, 0, stream>>>(coarse, beb, row_start, NBUK, E, n);
    partition_kernel<<<NCH, 1024, 0, stream>>>(esrc, edst, coarse, beb, rec, E, EPC, NBUK);
    fine_kernel<<<NBUK, 1024, 0, stream>>>(rec, beb, row_start, dis, csr_src, n);

    const uint32_t* hp = (const uint32_t*)h;
    int gGemm = (n + 127) / 128;
    int gGrp  = (n + 3) / 4;

    // ---- layer 0 (in = x row-major, no BN on input)
    gemm_kernel<128, false, false><<<gGemm, 512, 0, stream>>>(x, W0, nullptr, nullptr, h, n);
    agg_sliced_kernel<4><<<gGrp * 4, 256, 0, stream>>>(hp, row_start, csr_src, dis, b0, y, n);
    hipMemsetAsync(sums, 0, 128 * 4, stream);
    hipMemsetAsync(sumsq, 0, 128 * 4, stream);
    colsum_kernel<<<dim3(64, 4), 256, 0, stream>>>(y, n, sums, sumsq);
    finalize_kernel<128><<<1, 128, 0, stream>>>(sums, sumsq, g0, be0, sc, sh, (float)n);

    // ---- layer 1
    gemm_kernel<128, true, true><<<gGemm, 512, 0, stream>>>(y, W1, sc, sh, h, n);
    agg_sliced_kernel<4><<<gGrp * 4, 256, 0, stream>>>(hp, row_start, csr_src, dis, b1, y, n);
    hipMemsetAsync(sums, 0, 128 * 4, stream);
    hipMemsetAsync(sumsq, 0, 128 * 4, stream);
    colsum_kernel<<<dim3(64, 4), 256, 0, stream>>>(y, n, sums, sumsq);
    finalize_kernel<128><<<1, 128, 0, stream>>>(sums, sumsq, g1, be1, sc, sh, (float)n);

    // ---- layer 2 (F=64 -> 2 slices)
    gemm_kernel<64, true, true><<<gGemm, 512, 0, stream>>>(y, W2, sc, sh, h, n);
    agg_sliced_kernel<2><<<gGrp * 2, 256, 0, stream>>>(hp, row_start, csr_src, dis, b2, y, n);
    hipMemsetAsync(sums, 0, 64 * 4, stream);
    hipMemsetAsync(sumsq, 0, 64 * 4, stream);
    colsum_kernel<<<dim3(64, 2), 256, 0, stream>>>(y, n, sums, sumsq);
    finalize_kernel<64><<<1, 64, 0, stream>>>(sums, sumsq, g2, be2, sc, sh, (float)n);

    // ---- final BN2 + ELU -> out
    out_kernel<<<(n * 16 + 255) / 256, 256, 0, stream>>>(y, sc, sh, (float*)d_out, n);
}

// Round 7
// 545.306 us; speedup vs baseline: 1.0361x; 1.0361x over previous
//
#include <hip/hip_runtime.h>
#include <hip/hip_bf16.h>
#include <stdint.h>

// ---------------------------------------------------------------------------
// GNNEncoder: 3 x (GCNConv -> BatchNorm1d(train) -> ELU)
// N=50000, E=1.6M, dims 128->128->128->64
//
// R7: L2-sliced agg + PACKED CSR (coef precomputed in build).
//   csr_pk[e] = bf16(dis[src]*dis[dst])<<16 | src_u16  -- one 4B load gives
//   both the gather index and the edge coefficient; removes the per-slice
//   redundant dis gathers that made R6's agg VALU-heavy.
//   Build: counting sort (R5) with fine pass split into fine_a (row_start,
//   dis) and fine_b (packed csr placement; needs global dis complete).
//   h,y slice-major [S][n][32cols]; slice = bid & (S-1) pins 3.2MB in L2.
// ---------------------------------------------------------------------------

#define NCH 256   // edge chunks (partition blocks)

static __device__ __forceinline__ float bflo(uint32_t u) {
    union { uint32_t u; float f; } x; x.u = u << 16; return x.f;
}
static __device__ __forceinline__ float bfhi(uint32_t u) {
    union { uint32_t u; float f; } x; x.u = u & 0xffff0000u; return x.f;
}
static __device__ __forceinline__ uint16_t f2bf(float f) {
    union { float f; uint32_t u; } x; x.f = f;
    uint32_t r = x.u + 0x7fffu + ((x.u >> 16) & 1u);   // RNE
    return (uint16_t)(r >> 16);
}
static __device__ __forceinline__ float eluf(float v) {
    return v > 0.f ? v : expm1f(v);
}

// --------------------------------------------- P1: coarse histogram
__global__ __launch_bounds__(1024) void hist_coarse_kernel(
    const int* __restrict__ dst, uint32_t* __restrict__ coarse,
    int E, int EPC, int NBUK) {
    __shared__ uint32_t cnt[256];
    int b = blockIdx.x, t = threadIdx.x;
    if (t < 256) cnt[t] = 0;
    __syncthreads();
    int e0 = b * EPC, e1 = min(E, e0 + EPC);
    for (int e = e0 + t; e < e1; e += 1024) atomicAdd(&cnt[dst[e] >> 8], 1u);
    __syncthreads();
    if (t < NBUK) coarse[(size_t)t * NCH + b] = cnt[t];
}

// --------------------------------------------- P2: base scan (1 block)
__global__ __launch_bounds__(1024) void basescan_kernel(
    uint32_t* __restrict__ coarse, int* __restrict__ beb,
    int* __restrict__ row_start, int NBUK, int E, int n) {
    __shared__ int btot[256];
    __shared__ int wt[4];
    int t = threadIdx.x;
    int sum = 0;
    if (t < NBUK) {
        uint32_t* rowp = coarse + (size_t)t * NCH;
        uint32_t run = 0;
        for (int ch = 0; ch < NCH; ++ch) {
            uint32_t v = rowp[ch];
            rowp[ch] = run;
            run += v;
        }
        sum = (int)run;
    }
    if (t < 256) btot[t] = (t < NBUK) ? sum : 0;
    __syncthreads();
    int x = 0, v = 0;
    if (t < 256) {
        int lane = t & 63, w = t >> 6;
        v = btot[t];
        x = v;
        #pragma unroll
        for (int off = 1; off < 64; off <<= 1) {
            int m = __shfl_up(x, off);
            if (lane >= off) x += m;
        }
        if (lane == 63) wt[w] = x;
    }
    __syncthreads();
    if (t < 256) {
        int w = t >> 6, woff = 0;
        for (int j = 0; j < w; ++j) woff += wt[j];
        int excl = woff + x - v;
        if (t < NBUK) beb[t] = excl;
    }
    if (t == 0) {
        beb[NBUK] = E;
        row_start[n] = E;
    }
}

// --------------------------------------------- P3: partition into buckets
// rec = (dst&255)<<16 | src   (n <= 65536)
__global__ __launch_bounds__(1024) void partition_kernel(
    const int* __restrict__ src, const int* __restrict__ dst,
    const uint32_t* __restrict__ coarse, const int* __restrict__ beb,
    uint32_t* __restrict__ rec, int E, int EPC, int NBUK) {
    __shared__ int cur[256];
    int b = blockIdx.x, t = threadIdx.x;
    if (t < NBUK) cur[t] = (int)coarse[(size_t)t * NCH + b] + beb[t];
    __syncthreads();
    int e0 = b * EPC, e1 = min(E, e0 + EPC);
    for (int e = e0 + t; e < e1; e += 1024) {
        int d = dst[e];
        int pos = atomicAdd(&cur[d >> 8], 1);
        rec[pos] = (uint32_t)src[e] | ((uint32_t)(d & 255) << 16);
    }
}

// --------------------------------------------- P4a: per-bucket hist -> row_start, dis
__global__ __launch_bounds__(1024) void fine_a_kernel(
    const uint32_t* __restrict__ rec, const int* __restrict__ beb,
    int* __restrict__ row_start, float* __restrict__ dis, int n) {
    __shared__ int cnt[256];
    __shared__ int wt[4];
    int b = blockIdx.x, t = threadIdx.x;
    int e0 = beb[b], e1 = beb[b + 1];
    if (t < 256) cnt[t] = 0;
    __syncthreads();
    for (int i = e0 + t; i < e1; i += 1024)
        atomicAdd(&cnt[(rec[i] >> 16) & 255], 1);
    __syncthreads();
    int x = 0, deg = 0;
    if (t < 256) {
        int lane = t & 63, w = t >> 6;
        deg = cnt[t];
        x = deg;
        #pragma unroll
        for (int off = 1; off < 64; off <<= 1) {
            int m = __shfl_up(x, off);
            if (lane >= off) x += m;
        }
        if (lane == 63) wt[w] = x;
    }
    __syncthreads();
    if (t < 256) {
        int w = t >> 6, woff = 0;
        for (int j = 0; j < w; ++j) woff += wt[j];
        int excl = woff + x - deg;
        int node = (b << 8) + t;
        if (node < n) {
            row_start[node] = e0 + excl;
            dis[node] = rsqrtf(1.0f + (float)deg);
        }
    }
}

// --------------------------------------------- P4b: packed csr placement
// csr_pk[pos] = bf16(dis[dst]*dis[src])<<16 | src
__global__ __launch_bounds__(1024) void fine_b_kernel(
    const uint32_t* __restrict__ rec, const int* __restrict__ beb,
    const int* __restrict__ row_start, const float* __restrict__ dis,
    uint32_t* __restrict__ csr_pk, int n) {
    __shared__ int cur[256];
    __shared__ float dloc[256];
    int b = blockIdx.x, t = threadIdx.x;
    int e0 = beb[b], e1 = beb[b + 1];
    if (t < 256) {
        int node = (b << 8) + t;
        cur[t] = (node < n) ? row_start[node] : 0;
        dloc[t] = (node < n) ? dis[node] : 0.f;
    }
    __syncthreads();
    for (int i = e0 + t; i < e1; i += 1024) {
        uint32_t r = rec[i];
        int s = (int)(r & 0xffffu);
        int dl = (int)((r >> 16) & 255u);
        float c = dloc[dl] * dis[s];
        int pos = atomicAdd(&cur[dl], 1);
        csr_pk[pos] = ((uint32_t)f2bf(c) << 16) | (uint32_t)s;
    }
}

// ------------------------------------------------------------------- GEMM
// h (bf16, slice-major [F/32][n][32]) = act(in)[n][128] @ W[128][F]
// in: row-major [n][128] (layer 0) or slice-major [4][n][32] (layers 1,2).
template <int F, bool BN, bool SLICED_IN>
__global__ __launch_bounds__(512) void gemm_kernel(
    const float* __restrict__ in, const float* __restrict__ W,
    const float* __restrict__ sc, const float* __restrict__ sh,
    uint16_t* __restrict__ h, int n) {
    constexpr int K = 128;
    constexpr int BM = 128;
    __shared__ float xs[K][BM + 4];   // transposed: xs[k][r]
    __shared__ float ws[K][F];
    int t = threadIdx.x;
    int row0 = blockIdx.x * BM;

    for (int i = t * 4; i < K * F; i += 512 * 4) {
        *(float4*)((float*)ws + i) = *(const float4*)(W + i);
    }
    for (int idx = t; idx < BM * K / 4; idx += 512) {
        int r = idx >> 5;
        int k4 = (idx & 31) << 2;
        int gr = row0 + r;
        float4 v = make_float4(0.f, 0.f, 0.f, 0.f);
        if (gr < n) {
            const float* p;
            if (SLICED_IN)
                p = in + ((size_t)(k4 >> 5) * n + gr) * 32 + (k4 & 31);
            else
                p = in + (size_t)gr * K + k4;
            v = *(const float4*)p;
        }
        if (BN) {
            float4 s4 = *(const float4*)(sc + k4);
            float4 h4 = *(const float4*)(sh + k4);
            v.x = eluf(v.x * s4.x + h4.x);
            v.y = eluf(v.y * s4.y + h4.y);
            v.z = eluf(v.z * s4.z + h4.z);
            v.w = eluf(v.w * s4.w + h4.w);
        }
        xs[k4 + 0][r] = v.x;
        xs[k4 + 1][r] = v.y;
        xs[k4 + 2][r] = v.z;
        xs[k4 + 3][r] = v.w;
    }
    __syncthreads();

    constexpr int CW = F / 16;
    int tx = t & 15;
    int ty = t >> 4;
    float acc[4][CW];
    #pragma unroll
    for (int r = 0; r < 4; ++r)
        #pragma unroll
        for (int c = 0; c < CW; ++c) acc[r][c] = 0.f;

    for (int k = 0; k < K; ++k) {
        float4 xv = *(const float4*)&xs[k][ty * 4];
        float wv[CW];
        *(float4*)wv = *(const float4*)&ws[k][tx * CW];
        if (CW == 8) *(float4*)(wv + 4) = *(const float4*)&ws[k][tx * CW + 4];
        const float* xp = &xv.x;
        #pragma unroll
        for (int r = 0; r < 4; ++r)
            #pragma unroll
            for (int c = 0; c < CW; ++c)
                acc[r][c] = fmaf(xp[r], wv[c], acc[r][c]);
    }

    int col0 = tx * CW;
    int sl = col0 >> 5, off = col0 & 31;
    #pragma unroll
    for (int r = 0; r < 4; ++r) {
        int row = row0 + ty * 4 + r;
        if (row < n) {
            uint16_t* dstp = h + ((size_t)sl * n + row) * 32 + off;
            uint32_t p[CW / 2];
            #pragma unroll
            for (int c = 0; c < CW; c += 2)
                p[c / 2] = (uint32_t)f2bf(acc[r][c]) | ((uint32_t)f2bf(acc[r][c + 1]) << 16);
            if (CW == 8) *(uint4*)dstp = make_uint4(p[0], p[1], p[2], p[3]);
            else         *(uint2*)dstp = make_uint2(p[0], p[1]);
        }
    }
}

// -------------------------------------------------------------------- AGG
// Slice-major h [S][n][16 u32], y [S][n][32 f32]; slice = bid & (S-1).
// Wave = 1 node: 4 edge-groups x 16 lanes, unroll-4 (16 edges in flight).
// Packed csr: one 4B load -> gather index + bf16 coef (no dis gather).
template <int S>
__global__ __launch_bounds__(256) void agg_sliced_kernel(
    const uint32_t* __restrict__ hp,
    const int* __restrict__ row_start, const uint32_t* __restrict__ csr_pk,
    const float* __restrict__ dis, const float* __restrict__ bias,
    float* __restrict__ y, int n) {
    int bid = blockIdx.x;
    int sl = bid & (S - 1);
    int grp = bid / S;
    int wv = threadIdx.x >> 6;
    int lane = threadIdx.x & 63;
    int node = grp * 4 + wv;
    if (node >= n) return;
    int eg = lane >> 4, lig = lane & 15;
    int s = row_start[node], e = row_start[node + 1];
    const uint32_t* hs = hp + (size_t)sl * n * 16;
    float a0 = 0.f, a1 = 0.f;
    int i = s;
    for (; i + 16 <= e; i += 16) {
        uint32_t pk[4];
        #pragma unroll
        for (int st = 0; st < 4; ++st) pk[st] = csr_pk[i + st * 4 + eg];
        uint32_t u[4];
        #pragma unroll
        for (int st = 0; st < 4; ++st) u[st] = hs[(size_t)(pk[st] & 0xffffu) * 16 + lig];
        #pragma unroll
        for (int st = 0; st < 4; ++st) {
            float c = bfhi(pk[st]);
            a0 = fmaf(c, bflo(u[st]), a0);
            a1 = fmaf(c, bfhi(u[st]), a1);
        }
    }
    for (; i < e; i += 4) {
        int ei = i + eg;
        uint32_t pk = (ei < e) ? csr_pk[ei] : 0u;    // coef 0 -> no contribution
        uint32_t u = hs[(size_t)(pk & 0xffffu) * 16 + lig];
        float c = bfhi(pk);
        a0 = fmaf(c, bflo(u), a0);
        a1 = fmaf(c, bfhi(u), a1);
    }
    a0 += __shfl_xor(a0, 16); a1 += __shfl_xor(a1, 16);
    a0 += __shfl_xor(a0, 32); a1 += __shfl_xor(a1, 32);
    if (eg == 0) {
        float dd = dis[node];
        uint32_t u = hs[(size_t)node * 16 + lig];
        float c2 = dd * dd;
        int col = sl * 32 + lig * 2;
        a0 = fmaf(c2, bflo(u), a0) + bias[col];
        a1 = fmaf(c2, bfhi(u), a1) + bias[col + 1];
        *(float2*)(y + ((size_t)sl * n + node) * 32 + lig * 2) = make_float2(a0, a1);
    }
}

// ------------------------------------------------------------ BN statistics
// y slice-major [S][n][32]; grid = (rowChunks, S)
__global__ __launch_bounds__(256) void colsum_kernel(
    const float* __restrict__ y, int n,
    float* __restrict__ sums, float* __restrict__ sumsq) {
    int sl = blockIdx.y;
    const float* ys = y + (size_t)sl * n * 32;
    int t = threadIdx.x, cg = t & 7, rt = t >> 3;
    float4 s = make_float4(0.f, 0.f, 0.f, 0.f);
    float4 q = make_float4(0.f, 0.f, 0.f, 0.f);
    for (int row = blockIdx.x * 32 + rt; row < n; row += gridDim.x * 32) {
        float4 v = *(const float4*)(ys + (size_t)row * 32 + cg * 4);
        s.x += v.x; s.y += v.y; s.z += v.z; s.w += v.w;
        q.x += v.x * v.x; q.y += v.y * v.y; q.z += v.z * v.z; q.w += v.w * v.w;
    }
    __shared__ float4 rs[32][8], rq[32][8];
    rs[rt][cg] = s; rq[rt][cg] = q;
    __syncthreads();
    for (int st = 16; st > 0; st >>= 1) {
        if (rt < st) {
            float4 o = rs[rt + st][cg], p = rq[rt + st][cg];
            rs[rt][cg].x += o.x; rs[rt][cg].y += o.y;
            rs[rt][cg].z += o.z; rs[rt][cg].w += o.w;
            rq[rt][cg].x += p.x; rq[rt][cg].y += p.y;
            rq[rt][cg].z += p.z; rq[rt][cg].w += p.w;
        }
        __syncthreads();
    }
    if (rt == 0) {
        float4 fs = rs[0][cg], fq = rq[0][cg];
        int col = sl * 32 + cg * 4;
        atomicAdd(&sums[col + 0], fs.x); atomicAdd(&sums[col + 1], fs.y);
        atomicAdd(&sums[col + 2], fs.z); atomicAdd(&sums[col + 3], fs.w);
        atomicAdd(&sumsq[col + 0], fq.x); atomicAdd(&sumsq[col + 1], fq.y);
        atomicAdd(&sumsq[col + 2], fq.z); atomicAdd(&sumsq[col + 3], fq.w);
    }
}

template <int F>
__global__ void finalize_kernel(const float* __restrict__ sums,
                                const float* __restrict__ sumsq,
                                const float* __restrict__ g, const float* __restrict__ be,
                                float* __restrict__ sc, float* __restrict__ sh, float n) {
    int c = threadIdx.x;
    if (c < F) {
        float m = sums[c] / n;
        float v = sumsq[c] / n - m * m;           // biased variance
        float r = rsqrtf(v + 1e-5f);
        float scale = r * g[c];
        sc[c] = scale;
        sh[c] = be[c] - m * scale;
    }
}

// ----------------------------------------------------------- final BN+ELU
// y slice-major [2][n][32] -> out row-major [n][64]
__global__ __launch_bounds__(256) void out_kernel(
    const float* __restrict__ y, const float* __restrict__ sc,
    const float* __restrict__ sh, float* __restrict__ out, int n) {
    int idx = blockIdx.x * 256 + threadIdx.x;
    if (idx >= n * 16) return;
    int node = idx >> 4, q = idx & 15;
    int sl = q >> 3, wq = (q & 7) * 4;
    int col = sl * 32 + wq;
    float4 v = *(const float4*)(y + ((size_t)sl * n + node) * 32 + wq);
    float4 s4 = *(const float4*)(sc + col);
    float4 h4 = *(const float4*)(sh + col);
    v.x = eluf(v.x * s4.x + h4.x);
    v.y = eluf(v.y * s4.y + h4.y);
    v.z = eluf(v.z * s4.z + h4.z);
    v.w = eluf(v.w * s4.w + h4.w);
    *(float4*)(out + (size_t)node * 64 + q * 4) = v;
}

// ---------------------------------------------------------------------------
extern "C" void kernel_launch(void* const* d_in, const int* in_sizes, int n_in,
                              void* d_out, int out_size, void* d_ws, size_t ws_size,
                              hipStream_t stream) {
    const float* x   = (const float*)d_in[0];
    const int*   edge = (const int*)d_in[1];
    const float* W0 = (const float*)d_in[2];
    const float* b0 = (const float*)d_in[3];
    const float* g0 = (const float*)d_in[4];
    const float* be0 = (const float*)d_in[5];
    const float* W1 = (const float*)d_in[6];
    const float* b1 = (const float*)d_in[7];
    const float* g1 = (const float*)d_in[8];
    const float* be1 = (const float*)d_in[9];
    const float* W2 = (const float*)d_in[10];
    const float* b2 = (const float*)d_in[11];
    const float* g2 = (const float*)d_in[12];
    const float* be2 = (const float*)d_in[13];

    const int n = in_sizes[0] / 128;     // 50000
    const int E = in_sizes[1] / 2;       // 1600000
    const int* esrc = edge;
    const int* edst = edge + E;

    const int NBUK = (n + 255) >> 8;               // 256-node buckets (<=256)
    const int EPC  = (E + NCH - 1) / NCH;          // edges per chunk

    char* w = (char*)d_ws;
    auto carve = [&](size_t bytes) -> void* {
        void* p = (void*)w;
        w += (bytes + 255) & ~(size_t)255;
        return p;
    };
    float*    y         = (float*)carve((size_t)n * 128 * 4);     // slice-major
    uint16_t* h         = (uint16_t*)carve((size_t)n * 128 * 2);  // slice-major
    uint32_t* csr_pk    = (uint32_t*)carve((size_t)E * 4);
    uint32_t* rec       = (uint32_t*)carve((size_t)E * 4);
    uint32_t* coarse    = (uint32_t*)carve((size_t)NBUK * NCH * 4);
    int*      beb       = (int*)carve((size_t)(NBUK + 1) * 4);
    int*      row_start = (int*)carve((size_t)(n + 1) * 4);
    float*    dis       = (float*)carve((size_t)n * 4);
    float*    sums      = (float*)carve(128 * 4);
    float*    sumsq     = (float*)carve(128 * 4);
    float*    sc        = (float*)carve(128 * 4);
    float*    sh        = (float*)carve(128 * 4);

    // ---- CSR build: counting sort + packed coef
    hist_coarse_kernel<<<NCH, 1024, 0, stream>>>(edst, coarse, E, EPC, NBUK);
    basescan_kernel<<<1, 1024, 0, stream>>>(coarse, beb, row_start, NBUK, E, n);
    partition_kernel<<<NCH, 1024, 0, stream>>>(esrc, edst, coarse, beb, rec, E, EPC, NBUK);
    fine_a_kernel<<<NBUK, 1024, 0, stream>>>(rec, beb, row_start, dis, n);
    fine_b_kernel<<<NBUK, 1024, 0, stream>>>(rec, beb, row_start, dis, csr_pk, n);

    const uint32_t* hp = (const uint32_t*)h;
    int gGemm = (n + 127) / 128;
    int gGrp  = (n + 3) / 4;

    // ---- layer 0 (in = x row-major, no BN on input)
    gemm_kernel<128, false, false><<<gGemm, 512, 0, stream>>>(x, W0, nullptr, nullptr, h, n);
    agg_sliced_kernel<4><<<gGrp * 4, 256, 0, stream>>>(hp, row_start, csr_pk, dis, b0, y, n);
    hipMemsetAsync(sums, 0, 128 * 4, stream);
    hipMemsetAsync(sumsq, 0, 128 * 4, stream);
    colsum_kernel<<<dim3(64, 4), 256, 0, stream>>>(y, n, sums, sumsq);
    finalize_kernel<128><<<1, 128, 0, stream>>>(sums, sumsq, g0, be0, sc, sh, (float)n);

    // ---- layer 1
    gemm_kernel<128, true, true><<<gGemm, 512, 0, stream>>>(y, W1, sc, sh, h, n);
    agg_sliced_kernel<4><<<gGrp * 4, 256, 0, stream>>>(hp, row_start, csr_pk, dis, b1, y, n);
    hipMemsetAsync(sums, 0, 128 * 4, stream);
    hipMemsetAsync(sumsq, 0, 128 * 4, stream);
    colsum_kernel<<<dim3(64, 4), 256, 0, stream>>>(y, n, sums, sumsq);
    finalize_kernel<128><<<1, 128, 0, stream>>>(sums, sumsq, g1, be1, sc, sh, (float)n);

    // ---- layer 2 (F=64 -> 2 slices)
    gemm_kernel<64, true, true><<<gGemm, 512, 0, stream>>>(y, W2, sc, sh, h, n);
    agg_sliced_kernel<2><<<gGrp * 2, 256, 0, stream>>>(hp, row_start, csr_pk, dis, b2, y, n);
    hipMemsetAsync(sums, 0, 64 * 4, stream);
    hipMemsetAsync(sumsq, 0, 64 * 4, stream);
    colsum_kernel<<<dim3(64, 2), 256, 0, stream>>>(y, n, sums, sumsq);
    finalize_kernel<64><<<1, 64, 0, stream>>>(sums, sumsq, g2, be2, sc, sh, (float)n);

    // ---- final BN2 + ELU -> out
    out_kernel<<<(n * 16 + 255) / 256, 256, 0, stream>>>(y, sc, sh, (float*)d_out, n);
}

// Round 9
// 515.605 us; speedup vs baseline: 1.0957x; 1.0576x over previous
//
#include <hip/hip_runtime.h>
#include <hip/hip_bf16.h>
#include <stdint.h>

// ---------------------------------------------------------------------------
// GNNEncoder: 3 x (GCNConv -> BatchNorm1d(train) -> ELU)
// N=50000, E=1.6M, dims 128->128->128->64
//
// R9 = R8 resubmitted (GPU acquisition timed out; no measurement happened).
// R8: fat-gather agg. 4 lanes/edge x 16 edges/wave; each lane loads uint4
//   (16B) of the 64B slice row -> ONE gather instruction per 16 edges
//   (was 4), killing the L1 transaction bottleneck. 8 accumulators/lane,
//   shfl_xor reduce over edge groups.
//   Packed CSR (bf16 coef | src u16), counting-sort build, slice-major h/y:
//   unchanged from R7.
// ---------------------------------------------------------------------------

#define NCH 256   // edge chunks (partition blocks)

static __device__ __forceinline__ float bflo(uint32_t u) {
    union { uint32_t u; float f; } x; x.u = u << 16; return x.f;
}
static __device__ __forceinline__ float bfhi(uint32_t u) {
    union { uint32_t u; float f; } x; x.u = u & 0xffff0000u; return x.f;
}
static __device__ __forceinline__ uint16_t f2bf(float f) {
    union { float f; uint32_t u; } x; x.f = f;
    uint32_t r = x.u + 0x7fffu + ((x.u >> 16) & 1u);   // RNE
    return (uint16_t)(r >> 16);
}
static __device__ __forceinline__ float eluf(float v) {
    return v > 0.f ? v : expm1f(v);
}
static __device__ __forceinline__ void fma8(float c, uint4 u, float* a) {
    a[0] = fmaf(c, bflo(u.x), a[0]); a[1] = fmaf(c, bfhi(u.x), a[1]);
    a[2] = fmaf(c, bflo(u.y), a[2]); a[3] = fmaf(c, bfhi(u.y), a[3]);
    a[4] = fmaf(c, bflo(u.z), a[4]); a[5] = fmaf(c, bfhi(u.z), a[5]);
    a[6] = fmaf(c, bflo(u.w), a[6]); a[7] = fmaf(c, bfhi(u.w), a[7]);
}

// --------------------------------------------- P1: coarse histogram
__global__ __launch_bounds__(1024) void hist_coarse_kernel(
    const int* __restrict__ dst, uint32_t* __restrict__ coarse,
    int E, int EPC, int NBUK) {
    __shared__ uint32_t cnt[256];
    int b = blockIdx.x, t = threadIdx.x;
    if (t < 256) cnt[t] = 0;
    __syncthreads();
    int e0 = b * EPC, e1 = min(E, e0 + EPC);
    for (int e = e0 + t; e < e1; e += 1024) atomicAdd(&cnt[dst[e] >> 8], 1u);
    __syncthreads();
    if (t < NBUK) coarse[(size_t)t * NCH + b] = cnt[t];
}

// --------------------------------------------- P2: base scan (1 block)
__global__ __launch_bounds__(1024) void basescan_kernel(
    uint32_t* __restrict__ coarse, int* __restrict__ beb,
    int* __restrict__ row_start, int NBUK, int E, int n) {
    __shared__ int btot[256];
    __shared__ int wt[4];
    int t = threadIdx.x;
    int sum = 0;
    if (t < NBUK) {
        uint32_t* rowp = coarse + (size_t)t * NCH;
        uint32_t run = 0;
        for (int ch = 0; ch < NCH; ++ch) {
            uint32_t v = rowp[ch];
            rowp[ch] = run;
            run += v;
        }
        sum = (int)run;
    }
    if (t < 256) btot[t] = (t < NBUK) ? sum : 0;
    __syncthreads();
    int x = 0, v = 0;
    if (t < 256) {
        int lane = t & 63, w = t >> 6;
        v = btot[t];
        x = v;
        #pragma unroll
        for (int off = 1; off < 64; off <<= 1) {
            int m = __shfl_up(x, off);
            if (lane >= off) x += m;
        }
        if (lane == 63) wt[w] = x;
    }
    __syncthreads();
    if (t < 256) {
        int w = t >> 6, woff = 0;
        for (int j = 0; j < w; ++j) woff += wt[j];
        int excl = woff + x - v;
        if (t < NBUK) beb[t] = excl;
    }
    if (t == 0) {
        beb[NBUK] = E;
        row_start[n] = E;
    }
}

// --------------------------------------------- P3: partition into buckets
// rec = (dst&255)<<16 | src   (n <= 65536)
__global__ __launch_bounds__(1024) void partition_kernel(
    const int* __restrict__ src, const int* __restrict__ dst,
    const uint32_t* __restrict__ coarse, const int* __restrict__ beb,
    uint32_t* __restrict__ rec, int E, int EPC, int NBUK) {
    __shared__ int cur[256];
    int b = blockIdx.x, t = threadIdx.x;
    if (t < NBUK) cur[t] = (int)coarse[(size_t)t * NCH + b] + beb[t];
    __syncthreads();
    int e0 = b * EPC, e1 = min(E, e0 + EPC);
    for (int e = e0 + t; e < e1; e += 1024) {
        int d = dst[e];
        int pos = atomicAdd(&cur[d >> 8], 1);
        rec[pos] = (uint32_t)src[e] | ((uint32_t)(d & 255) << 16);
    }
}

// --------------------------------------------- P4a: per-bucket hist -> row_start, dis
__global__ __launch_bounds__(1024) void fine_a_kernel(
    const uint32_t* __restrict__ rec, const int* __restrict__ beb,
    int* __restrict__ row_start, float* __restrict__ dis, int n) {
    __shared__ int cnt[256];
    __shared__ int wt[4];
    int b = blockIdx.x, t = threadIdx.x;
    int e0 = beb[b], e1 = beb[b + 1];
    if (t < 256) cnt[t] = 0;
    __syncthreads();
    for (int i = e0 + t; i < e1; i += 1024)
        atomicAdd(&cnt[(rec[i] >> 16) & 255], 1);
    __syncthreads();
    int x = 0, deg = 0;
    if (t < 256) {
        int lane = t & 63, w = t >> 6;
        deg = cnt[t];
        x = deg;
        #pragma unroll
        for (int off = 1; off < 64; off <<= 1) {
            int m = __shfl_up(x, off);
            if (lane >= off) x += m;
        }
        if (lane == 63) wt[w] = x;
    }
    __syncthreads();
    if (t < 256) {
        int w = t >> 6, woff = 0;
        for (int j = 0; j < w; ++j) woff += wt[j];
        int excl = woff + x - deg;
        int node = (b << 8) + t;
        if (node < n) {
            row_start[node] = e0 + excl;
            dis[node] = rsqrtf(1.0f + (float)deg);
        }
    }
}

// --------------------------------------------- P4b: packed csr placement
// csr_pk[pos] = bf16(dis[dst]*dis[src])<<16 | src
__global__ __launch_bounds__(1024) void fine_b_kernel(
    const uint32_t* __restrict__ rec, const int* __restrict__ beb,
    const int* __restrict__ row_start, const float* __restrict__ dis,
    uint32_t* __restrict__ csr_pk, int n) {
    __shared__ int cur[256];
    __shared__ float dloc[256];
    int b = blockIdx.x, t = threadIdx.x;
    int e0 = beb[b], e1 = beb[b + 1];
    if (t < 256) {
        int node = (b << 8) + t;
        cur[t] = (node < n) ? row_start[node] : 0;
        dloc[t] = (node < n) ? dis[node] : 0.f;
    }
    __syncthreads();
    for (int i = e0 + t; i < e1; i += 1024) {
        uint32_t r = rec[i];
        int s = (int)(r & 0xffffu);
        int dl = (int)((r >> 16) & 255u);
        float c = dloc[dl] * dis[s];
        int pos = atomicAdd(&cur[dl], 1);
        csr_pk[pos] = ((uint32_t)f2bf(c) << 16) | (uint32_t)s;
    }
}

// ------------------------------------------------------------------- GEMM
// h (bf16, slice-major [F/32][n][32]) = act(in)[n][128] @ W[128][F]
// in: row-major [n][128] (layer 0) or slice-major [4][n][32] (layers 1,2).
template <int F, bool BN, bool SLICED_IN>
__global__ __launch_bounds__(512) void gemm_kernel(
    const float* __restrict__ in, const float* __restrict__ W,
    const float* __restrict__ sc, const float* __restrict__ sh,
    uint16_t* __restrict__ h, int n) {
    constexpr int K = 128;
    constexpr int BM = 128;
    __shared__ float xs[K][BM + 4];   // transposed: xs[k][r]
    __shared__ float ws[K][F];
    int t = threadIdx.x;
    int row0 = blockIdx.x * BM;

    for (int i = t * 4; i < K * F; i += 512 * 4) {
        *(float4*)((float*)ws + i) = *(const float4*)(W + i);
    }
    for (int idx = t; idx < BM * K / 4; idx += 512) {
        int r = idx >> 5;
        int k4 = (idx & 31) << 2;
        int gr = row0 + r;
        float4 v = make_float4(0.f, 0.f, 0.f, 0.f);
        if (gr < n) {
            const float* p;
            if (SLICED_IN)
                p = in + ((size_t)(k4 >> 5) * n + gr) * 32 + (k4 & 31);
            else
                p = in + (size_t)gr * K + k4;
            v = *(const float4*)p;
        }
        if (BN) {
            float4 s4 = *(const float4*)(sc + k4);
            float4 h4 = *(const float4*)(sh + k4);
            v.x = eluf(v.x * s4.x + h4.x);
            v.y = eluf(v.y * s4.y + h4.y);
            v.z = eluf(v.z * s4.z + h4.z);
            v.w = eluf(v.w * s4.w + h4.w);
        }
        xs[k4 + 0][r] = v.x;
        xs[k4 + 1][r] = v.y;
        xs[k4 + 2][r] = v.z;
        xs[k4 + 3][r] = v.w;
    }
    __syncthreads();

    constexpr int CW = F / 16;
    int tx = t & 15;
    int ty = t >> 4;
    float acc[4][CW];
    #pragma unroll
    for (int r = 0; r < 4; ++r)
        #pragma unroll
        for (int c = 0; c < CW; ++c) acc[r][c] = 0.f;

    for (int k = 0; k < K; ++k) {
        float4 xv = *(const float4*)&xs[k][ty * 4];
        float wv[CW];
        *(float4*)wv = *(const float4*)&ws[k][tx * CW];
        if (CW == 8) *(float4*)(wv + 4) = *(const float4*)&ws[k][tx * CW + 4];
        const float* xp = &xv.x;
        #pragma unroll
        for (int r = 0; r < 4; ++r)
            #pragma unroll
            for (int c = 0; c < CW; ++c)
                acc[r][c] = fmaf(xp[r], wv[c], acc[r][c]);
    }

    int col0 = tx * CW;
    int sl = col0 >> 5, off = col0 & 31;
    #pragma unroll
    for (int r = 0; r < 4; ++r) {
        int row = row0 + ty * 4 + r;
        if (row < n) {
            uint16_t* dstp = h + ((size_t)sl * n + row) * 32 + off;
            uint32_t p[CW / 2];
            #pragma unroll
            for (int c = 0; c < CW; c += 2)
                p[c / 2] = (uint32_t)f2bf(acc[r][c]) | ((uint32_t)f2bf(acc[r][c + 1]) << 16);
            if (CW == 8) *(uint4*)dstp = make_uint4(p[0], p[1], p[2], p[3]);
            else         *(uint2*)dstp = make_uint2(p[0], p[1]);
        }
    }
}

// -------------------------------------------------------------------- AGG
// Slice-major h [S][n][32 bf16], y [S][n][32 f32]; slice = bid & (S-1).
// Wave = 1 node: 16 edge-groups x 4 lanes; each lane loads uint4 = 16B of
// the 64B row (one gather instr per 16 edges). 8 accumulators/lane,
// shfl_xor reduce over edge-groups (offsets 4..32).
template <int S>
__global__ __launch_bounds__(256) void agg_sliced_kernel(
    const uint16_t* __restrict__ h,
    const int* __restrict__ row_start, const uint32_t* __restrict__ csr_pk,
    const float* __restrict__ dis, const float* __restrict__ bias,
    float* __restrict__ y, int n) {
    int bid = blockIdx.x;
    int sl = bid & (S - 1);
    int grp = bid / S;
    int wv = threadIdx.x >> 6;
    int lane = threadIdx.x & 63;
    int node = grp * 4 + wv;
    if (node >= n) return;
    int eg = lane >> 2;          // 16 edge groups
    int lig = lane & 3;          // 4 col groups (16B each)
    int s = row_start[node], e = row_start[node + 1];
    const uint4* hs4 = (const uint4*)(h + (size_t)sl * n * 32);
    float a[8];
    #pragma unroll
    for (int j = 0; j < 8; ++j) a[j] = 0.f;
    int i = s;
    for (; i + 32 <= e; i += 32) {
        uint32_t pk0 = csr_pk[i + eg];
        uint32_t pk1 = csr_pk[i + 16 + eg];
        uint4 u0 = hs4[(size_t)(pk0 & 0xffffu) * 4 + lig];
        uint4 u1 = hs4[(size_t)(pk1 & 0xffffu) * 4 + lig];
        fma8(bfhi(pk0), u0, a);
        fma8(bfhi(pk1), u1, a);
    }
    for (; i + 16 <= e; i += 16) {
        uint32_t pk = csr_pk[i + eg];
        uint4 u = hs4[(size_t)(pk & 0xffffu) * 4 + lig];
        fma8(bfhi(pk), u, a);
    }
    if (i < e) {
        int ei = i + eg;
        uint32_t pk = (ei < e) ? csr_pk[ei] : 0u;   // coef +0 -> no contribution
        uint4 u = hs4[(size_t)(pk & 0xffffu) * 4 + lig];
        fma8(bfhi(pk), u, a);
    }
    #pragma unroll
    for (int off = 4; off < 64; off <<= 1)
        #pragma unroll
        for (int j = 0; j < 8; ++j) a[j] += __shfl_xor(a[j], off);
    if (eg == 0) {
        float dd = dis[node];
        uint4 u = hs4[(size_t)node * 4 + lig];
        fma8(dd * dd, u, a);
        const float* bp = bias + sl * 32 + lig * 8;
        float4 b0 = *(const float4*)bp;
        float4 b1 = *(const float4*)(bp + 4);
        float* yp = y + ((size_t)sl * n + node) * 32 + lig * 8;
        *(float4*)yp       = make_float4(a[0] + b0.x, a[1] + b0.y, a[2] + b0.z, a[3] + b0.w);
        *(float4*)(yp + 4) = make_float4(a[4] + b1.x, a[5] + b1.y, a[6] + b1.z, a[7] + b1.w);
    }
}

// ------------------------------------------------------------ BN statistics
// y slice-major [S][n][32]; grid = (rowChunks, S)
__global__ __launch_bounds__(256) void colsum_kernel(
    const float* __restrict__ y, int n,
    float* __restrict__ sums, float* __restrict__ sumsq) {
    int sl = blockIdx.y;
    const float* ys = y + (size_t)sl * n * 32;
    int t = threadIdx.x, cg = t & 7, rt = t >> 3;
    float4 s = make_float4(0.f, 0.f, 0.f, 0.f);
    float4 q = make_float4(0.f, 0.f, 0.f, 0.f);
    for (int row = blockIdx.x * 32 + rt; row < n; row += gridDim.x * 32) {
        float4 v = *(const float4*)(ys + (size_t)row * 32 + cg * 4);
        s.x += v.x; s.y += v.y; s.z += v.z; s.w += v.w;
        q.x += v.x * v.x; q.y += v.y * v.y; q.z += v.z * v.z; q.w += v.w * v.w;
    }
    __shared__ float4 rs[32][8], rq[32][8];
    rs[rt][cg] = s; rq[rt][cg] = q;
    __syncthreads();
    for (int st = 16; st > 0; st >>= 1) {
        if (rt < st) {
            float4 o = rs[rt + st][cg], p = rq[rt + st][cg];
            rs[rt][cg].x += o.x; rs[rt][cg].y += o.y;
            rs[rt][cg].z += o.z; rs[rt][cg].w += o.w;
            rq[rt][cg].x += p.x; rq[rt][cg].y += p.y;
            rq[rt][cg].z += p.z; rq[rt][cg].w += p.w;
        }
        __syncthreads();
    }
    if (rt == 0) {
        float4 fs = rs[0][cg], fq = rq[0][cg];
        int col = sl * 32 + cg * 4;
        atomicAdd(&sums[col + 0], fs.x); atomicAdd(&sums[col + 1], fs.y);
        atomicAdd(&sums[col + 2], fs.z); atomicAdd(&sums[col + 3], fs.w);
        atomicAdd(&sumsq[col + 0], fq.x); atomicAdd(&sumsq[col + 1], fq.y);
        atomicAdd(&sumsq[col + 2], fq.z); atomicAdd(&sumsq[col + 3], fq.w);
    }
}

template <int F>
__global__ void finalize_kernel(const float* __restrict__ sums,
                                const float* __restrict__ sumsq,
                                const float* __restrict__ g, const float* __restrict__ be,
                                float* __restrict__ sc, float* __restrict__ sh, float n) {
    int c = threadIdx.x;
    if (c < F) {
        float m = sums[c] / n;
        float v = sumsq[c] / n - m * m;           // biased variance
        float r = rsqrtf(v + 1e-5f);
        float scale = r * g[c];
        sc[c] = scale;
        sh[c] = be[c] - m * scale;
    }
}

// ----------------------------------------------------------- final BN+ELU
// y slice-major [2][n][32] -> out row-major [n][64]
__global__ __launch_bounds__(256) void out_kernel(
    const float* __restrict__ y, const float* __restrict__ sc,
    const float* __restrict__ sh, float* __restrict__ out, int n) {
    int idx = blockIdx.x * 256 + threadIdx.x;
    if (idx >= n * 16) return;
    int node = idx >> 4, q = idx & 15;
    int sl = q >> 3, wq = (q & 7) * 4;
    int col = sl * 32 + wq;
    float4 v = *(const float4*)(y + ((size_t)sl * n + node) * 32 + wq);
    float4 s4 = *(const float4*)(sc + col);
    float4 h4 = *(const float4*)(sh + col);
    v.x = eluf(v.x * s4.x + h4.x);
    v.y = eluf(v.y * s4.y + h4.y);
    v.z = eluf(v.z * s4.z + h4.z);
    v.w = eluf(v.w * s4.w + h4.w);
    *(float4*)(out + (size_t)node * 64 + q * 4) = v;
}

// ---------------------------------------------------------------------------
extern "C" void kernel_launch(void* const* d_in, const int* in_sizes, int n_in,
                              void* d_out, int out_size, void* d_ws, size_t ws_size,
                              hipStream_t stream) {
    const float* x   = (const float*)d_in[0];
    const int*   edge = (const int*)d_in[1];
    const float* W0 = (const float*)d_in[2];
    const float* b0 = (const float*)d_in[3];
    const float* g0 = (const float*)d_in[4];
    const float* be0 = (const float*)d_in[5];
    const float* W1 = (const float*)d_in[6];
    const float* b1 = (const float*)d_in[7];
    const float* g1 = (const float*)d_in[8];
    const float* be1 = (const float*)d_in[9];
    const float* W2 = (const float*)d_in[10];
    const float* b2 = (const float*)d_in[11];
    const float* g2 = (const float*)d_in[12];
    const float* be2 = (const float*)d_in[13];

    const int n = in_sizes[0] / 128;     // 50000
    const int E = in_sizes[1] / 2;       // 1600000
    const int* esrc = edge;
    const int* edst = edge + E;

    const int NBUK = (n + 255) >> 8;               // 256-node buckets (<=256)
    const int EPC  = (E + NCH - 1) / NCH;          // edges per chunk

    char* w = (char*)d_ws;
    auto carve = [&](size_t bytes) -> void* {
        void* p = (void*)w;
        w += (bytes + 255) & ~(size_t)255;
        return p;
    };
    float*    y         = (float*)carve((size_t)n * 128 * 4);     // slice-major
    uint16_t* h         = (uint16_t*)carve((size_t)n * 128 * 2);  // slice-major
    uint32_t* csr_pk    = (uint32_t*)carve((size_t)E * 4);
    uint32_t* rec       = (uint32_t*)carve((size_t)E * 4);
    uint32_t* coarse    = (uint32_t*)carve((size_t)NBUK * NCH * 4);
    int*      beb       = (int*)carve((size_t)(NBUK + 1) * 4);
    int*      row_start = (int*)carve((size_t)(n + 1) * 4);
    float*    dis       = (float*)carve((size_t)n * 4);
    float*    sums      = (float*)carve(128 * 4);
    float*    sumsq     = (float*)carve(128 * 4);
    float*    sc        = (float*)carve(128 * 4);
    float*    sh        = (float*)carve(128 * 4);

    // ---- CSR build: counting sort + packed coef
    hist_coarse_kernel<<<NCH, 1024, 0, stream>>>(edst, coarse, E, EPC, NBUK);
    basescan_kernel<<<1, 1024, 0, stream>>>(coarse, beb, row_start, NBUK, E, n);
    partition_kernel<<<NCH, 1024, 0, stream>>>(esrc, edst, coarse, beb, rec, E, EPC, NBUK);
    fine_a_kernel<<<NBUK, 1024, 0, stream>>>(rec, beb, row_start, dis, n);
    fine_b_kernel<<<NBUK, 1024, 0, stream>>>(rec, beb, row_start, dis, csr_pk, n);

    int gGemm = (n + 127) / 128;
    int gGrp  = (n + 3) / 4;

    // ---- layer 0 (in = x row-major, no BN on input)
    gemm_kernel<128, false, false><<<gGemm, 512, 0, stream>>>(x, W0, nullptr, nullptr, h, n);
    agg_sliced_kernel<4><<<gGrp * 4, 256, 0, stream>>>(h, row_start, csr_pk, dis, b0, y, n);
    hipMemsetAsync(sums, 0, 128 * 4, stream);
    hipMemsetAsync(sumsq, 0, 128 * 4, stream);
    colsum_kernel<<<dim3(64, 4), 256, 0, stream>>>(y, n, sums, sumsq);
    finalize_kernel<128><<<1, 128, 0, stream>>>(sums, sumsq, g0, be0, sc, sh, (float)n);

    // ---- layer 1
    gemm_kernel<128, true, true><<<gGemm, 512, 0, stream>>>(y, W1, sc, sh, h, n);
    agg_sliced_kernel<4><<<gGrp * 4, 256, 0, stream>>>(h, row_start, csr_pk, dis, b1, y, n);
    hipMemsetAsync(sums, 0, 128 * 4, stream);
    hipMemsetAsync(sumsq, 0, 128 * 4, stream);
    colsum_kernel<<<dim3(64, 4), 256, 0, stream>>>(y, n, sums, sumsq);
    finalize_kernel<128><<<1, 128, 0, stream>>>(sums, sumsq, g1, be1, sc, sh, (float)n);

    // ---- layer 2 (F=64 -> 2 slices)
    gemm_kernel<64, true, true><<<gGemm, 512, 0, stream>>>(y, W2, sc, sh, h, n);
    agg_sliced_kernel<2><<<gGrp * 2, 256, 0, stream>>>(h, row_start, csr_pk, dis, b2, y, n);
    hipMemsetAsync(sums, 0, 64 * 4, stream);
    hipMemsetAsync(sumsq, 0, 64 * 4, stream);
    colsum_kernel<<<dim3(64, 2), 256, 0, stream>>>(y, n, sums, sumsq);
    finalize_kernel<64><<<1, 64, 0, stream>>>(sums, sumsq, g2, be2, sc, sh, (float)n);

    // ---- final BN2 + ELU -> out
    out_kernel<<<(n * 16 + 255) / 256, 256, 0, stream>>>(y, sc, sh, (float*)d_out, n);
}

// Round 10
// 468.953 us; speedup vs baseline: 1.2047x; 1.0995x over previous
//
#include <hip/hip_runtime.h>
#include <hip/hip_bf16.h>
#include <stdint.h>

// ---------------------------------------------------------------------------
// GNNEncoder: 3 x (GCNConv -> BatchNorm1d(train) -> ELU)
// N=50000, E=1.6M, dims 128->128->128->64
//
// R10: reduction-free sliced agg.
//   Wave = 4 nodes x 16 lanes; lane owns (node, col-dword) for the whole
//   edge list -> no shfl reduction, no divergent epilogue (R9's per-wave
//   overhead was the bottleneck: 200K waves x ~130 fixed instrs).
//   Unroll-4 packed-CSR loop: 4 pk loads + 4 dword gathers in flight.
//   Slice-major h/y (S slices of 32 cols; 3.2MB slice pins in XCD L2).
//   GEMM: xs pad BM+4 -> BM+1 (write-phase bank conflict 16-way -> 4-way).
//   CSR build: counting sort + packed bf16-coef CSR (unchanged from R9).
// ---------------------------------------------------------------------------

#define NCH 256   // edge chunks (partition blocks)

static __device__ __forceinline__ float bflo(uint32_t u) {
    union { uint32_t u; float f; } x; x.u = u << 16; return x.f;
}
static __device__ __forceinline__ float bfhi(uint32_t u) {
    union { uint32_t u; float f; } x; x.u = u & 0xffff0000u; return x.f;
}
static __device__ __forceinline__ uint16_t f2bf(float f) {
    union { float f; uint32_t u; } x; x.f = f;
    uint32_t r = x.u + 0x7fffu + ((x.u >> 16) & 1u);   // RNE
    return (uint16_t)(r >> 16);
}
static __device__ __forceinline__ float eluf(float v) {
    return v > 0.f ? v : expm1f(v);
}

// --------------------------------------------- P1: coarse histogram
__global__ __launch_bounds__(1024) void hist_coarse_kernel(
    const int* __restrict__ dst, uint32_t* __restrict__ coarse,
    int E, int EPC, int NBUK) {
    __shared__ uint32_t cnt[256];
    int b = blockIdx.x, t = threadIdx.x;
    if (t < 256) cnt[t] = 0;
    __syncthreads();
    int e0 = b * EPC, e1 = min(E, e0 + EPC);
    for (int e = e0 + t; e < e1; e += 1024) atomicAdd(&cnt[dst[e] >> 8], 1u);
    __syncthreads();
    if (t < NBUK) coarse[(size_t)t * NCH + b] = cnt[t];
}

// --------------------------------------------- P2: base scan (1 block)
__global__ __launch_bounds__(1024) void basescan_kernel(
    uint32_t* __restrict__ coarse, int* __restrict__ beb,
    int* __restrict__ row_start, int NBUK, int E, int n) {
    __shared__ int btot[256];
    __shared__ int wt[4];
    int t = threadIdx.x;
    int sum = 0;
    if (t < NBUK) {
        uint32_t* rowp = coarse + (size_t)t * NCH;
        uint32_t run = 0;
        for (int ch = 0; ch < NCH; ++ch) {
            uint32_t v = rowp[ch];
            rowp[ch] = run;
            run += v;
        }
        sum = (int)run;
    }
    if (t < 256) btot[t] = (t < NBUK) ? sum : 0;
    __syncthreads();
    int x = 0, v = 0;
    if (t < 256) {
        int lane = t & 63, w = t >> 6;
        v = btot[t];
        x = v;
        #pragma unroll
        for (int off = 1; off < 64; off <<= 1) {
            int m = __shfl_up(x, off);
            if (lane >= off) x += m;
        }
        if (lane == 63) wt[w] = x;
    }
    __syncthreads();
    if (t < 256) {
        int w = t >> 6, woff = 0;
        for (int j = 0; j < w; ++j) woff += wt[j];
        int excl = woff + x - v;
        if (t < NBUK) beb[t] = excl;
    }
    if (t == 0) {
        beb[NBUK] = E;
        row_start[n] = E;
    }
}

// --------------------------------------------- P3: partition into buckets
// rec = (dst&255)<<16 | src   (n <= 65536)
__global__ __launch_bounds__(1024) void partition_kernel(
    const int* __restrict__ src, const int* __restrict__ dst,
    const uint32_t* __restrict__ coarse, const int* __restrict__ beb,
    uint32_t* __restrict__ rec, int E, int EPC, int NBUK) {
    __shared__ int cur[256];
    int b = blockIdx.x, t = threadIdx.x;
    if (t < NBUK) cur[t] = (int)coarse[(size_t)t * NCH + b] + beb[t];
    __syncthreads();
    int e0 = b * EPC, e1 = min(E, e0 + EPC);
    for (int e = e0 + t; e < e1; e += 1024) {
        int d = dst[e];
        int pos = atomicAdd(&cur[d >> 8], 1);
        rec[pos] = (uint32_t)src[e] | ((uint32_t)(d & 255) << 16);
    }
}

// --------------------------------------------- P4a: per-bucket hist -> row_start, dis
__global__ __launch_bounds__(1024) void fine_a_kernel(
    const uint32_t* __restrict__ rec, const int* __restrict__ beb,
    int* __restrict__ row_start, float* __restrict__ dis, int n) {
    __shared__ int cnt[256];
    __shared__ int wt[4];
    int b = blockIdx.x, t = threadIdx.x;
    int e0 = beb[b], e1 = beb[b + 1];
    if (t < 256) cnt[t] = 0;
    __syncthreads();
    for (int i = e0 + t; i < e1; i += 1024)
        atomicAdd(&cnt[(rec[i] >> 16) & 255], 1);
    __syncthreads();
    int x = 0, deg = 0;
    if (t < 256) {
        int lane = t & 63, w = t >> 6;
        deg = cnt[t];
        x = deg;
        #pragma unroll
        for (int off = 1; off < 64; off <<= 1) {
            int m = __shfl_up(x, off);
            if (lane >= off) x += m;
        }
        if (lane == 63) wt[w] = x;
    }
    __syncthreads();
    if (t < 256) {
        int w = t >> 6, woff = 0;
        for (int j = 0; j < w; ++j) woff += wt[j];
        int excl = woff + x - deg;
        int node = (b << 8) + t;
        if (node < n) {
            row_start[node] = e0 + excl;
            dis[node] = rsqrtf(1.0f + (float)deg);
        }
    }
}

// --------------------------------------------- P4b: packed csr placement
// csr_pk[pos] = bf16(dis[dst]*dis[src])<<16 | src
__global__ __launch_bounds__(1024) void fine_b_kernel(
    const uint32_t* __restrict__ rec, const int* __restrict__ beb,
    const int* __restrict__ row_start, const float* __restrict__ dis,
    uint32_t* __restrict__ csr_pk, int n) {
    __shared__ int cur[256];
    __shared__ float dloc[256];
    int b = blockIdx.x, t = threadIdx.x;
    int e0 = beb[b], e1 = beb[b + 1];
    if (t < 256) {
        int node = (b << 8) + t;
        cur[t] = (node < n) ? row_start[node] : 0;
        dloc[t] = (node < n) ? dis[node] : 0.f;
    }
    __syncthreads();
    for (int i = e0 + t; i < e1; i += 1024) {
        uint32_t r = rec[i];
        int s = (int)(r & 0xffffu);
        int dl = (int)((r >> 16) & 255u);
        float c = dloc[dl] * dis[s];
        int pos = atomicAdd(&cur[dl], 1);
        csr_pk[pos] = ((uint32_t)f2bf(c) << 16) | (uint32_t)s;
    }
}

// ------------------------------------------------------------------- GEMM
// h (bf16, slice-major [F/32][n][32]) = act(in)[n][128] @ W[128][F]
// in: row-major [n][128] (layer 0) or slice-major [4][n][32] (layers 1,2).
template <int F, bool BN, bool SLICED_IN>
__global__ __launch_bounds__(512) void gemm_kernel(
    const float* __restrict__ in, const float* __restrict__ W,
    const float* __restrict__ sc, const float* __restrict__ sh,
    uint16_t* __restrict__ h, int n) {
    constexpr int K = 128;
    constexpr int BM = 128;
    __shared__ float xs[K][BM + 1];   // stride 129: write-phase 4-way (was 16-way at +4)
    __shared__ float ws[K][F];
    int t = threadIdx.x;
    int row0 = blockIdx.x * BM;

    for (int i = t * 4; i < K * F; i += 512 * 4) {
        *(float4*)((float*)ws + i) = *(const float4*)(W + i);
    }
    for (int idx = t; idx < BM * K / 4; idx += 512) {
        int r = idx >> 5;
        int k4 = (idx & 31) << 2;
        int gr = row0 + r;
        float4 v = make_float4(0.f, 0.f, 0.f, 0.f);
        if (gr < n) {
            const float* p;
            if (SLICED_IN)
                p = in + ((size_t)(k4 >> 5) * n + gr) * 32 + (k4 & 31);
            else
                p = in + (size_t)gr * K + k4;
            v = *(const float4*)p;
        }
        if (BN) {
            float4 s4 = *(const float4*)(sc + k4);
            float4 h4 = *(const float4*)(sh + k4);
            v.x = eluf(v.x * s4.x + h4.x);
            v.y = eluf(v.y * s4.y + h4.y);
            v.z = eluf(v.z * s4.z + h4.z);
            v.w = eluf(v.w * s4.w + h4.w);
        }
        xs[k4 + 0][r] = v.x;
        xs[k4 + 1][r] = v.y;
        xs[k4 + 2][r] = v.z;
        xs[k4 + 3][r] = v.w;
    }
    __syncthreads();

    constexpr int CW = F / 16;
    int tx = t & 15;
    int ty = t >> 4;
    float acc[4][CW];
    #pragma unroll
    for (int r = 0; r < 4; ++r)
        #pragma unroll
        for (int c = 0; c < CW; ++c) acc[r][c] = 0.f;

    for (int k = 0; k < K; ++k) {
        float4 xv = *(const float4*)&xs[k][ty * 4];
        float wv[CW];
        *(float4*)wv = *(const float4*)&ws[k][tx * CW];
        if (CW == 8) *(float4*)(wv + 4) = *(const float4*)&ws[k][tx * CW + 4];
        const float* xp = &xv.x;
        #pragma unroll
        for (int r = 0; r < 4; ++r)
            #pragma unroll
            for (int c = 0; c < CW; ++c)
                acc[r][c] = fmaf(xp[r], wv[c], acc[r][c]);
    }

    int col0 = tx * CW;
    int sl = col0 >> 5, off = col0 & 31;
    #pragma unroll
    for (int r = 0; r < 4; ++r) {
        int row = row0 + ty * 4 + r;
        if (row < n) {
            uint16_t* dstp = h + ((size_t)sl * n + row) * 32 + off;
            uint32_t p[CW / 2];
            #pragma unroll
            for (int c = 0; c < CW; c += 2)
                p[c / 2] = (uint32_t)f2bf(acc[r][c]) | ((uint32_t)f2bf(acc[r][c + 1]) << 16);
            if (CW == 8) *(uint4*)dstp = make_uint4(p[0], p[1], p[2], p[3]);
            else         *(uint2*)dstp = make_uint2(p[0], p[1]);
        }
    }
}

// -------------------------------------------------------------------- AGG
// Reduction-free: wave = 4 nodes x 16 lanes; lane owns (node, col-dword)
// across the whole edge list. Unroll-4 packed-CSR: 4 pk loads + 4 dword
// gathers in flight. Slice-major h [S][n][16 u32], y [S][n][32 f32];
// slice = bid & (S-1) -> consecutive blocks on different XCDs pin slices.
template <int S>
__global__ __launch_bounds__(256) void agg_sliced_kernel(
    const uint32_t* __restrict__ hp,
    const int* __restrict__ row_start, const uint32_t* __restrict__ csr_pk,
    const float* __restrict__ dis, const float* __restrict__ bias,
    float* __restrict__ y, int n) {
    int bid = blockIdx.x;
    int sl = bid & (S - 1);
    int grp = bid / S;                 // 16-node group
    int wv = threadIdx.x >> 6;
    int lane = threadIdx.x & 63;
    int ng = lane >> 4;                // node within wave (0..3)
    int lig = lane & 15;               // col dword (2 bf16 cols)
    int node = grp * 16 + wv * 4 + ng;
    if (node >= n) return;
    int s = row_start[node], e = row_start[node + 1];
    const uint32_t* hs = hp + (size_t)sl * n * 16;
    float a0 = 0.f, a1 = 0.f;
    int i = s;
    for (; i + 4 <= e; i += 4) {
        uint32_t pk0 = csr_pk[i];
        uint32_t pk1 = csr_pk[i + 1];
        uint32_t pk2 = csr_pk[i + 2];
        uint32_t pk3 = csr_pk[i + 3];
        uint32_t u0 = hs[(size_t)(pk0 & 0xffffu) * 16 + lig];
        uint32_t u1 = hs[(size_t)(pk1 & 0xffffu) * 16 + lig];
        uint32_t u2 = hs[(size_t)(pk2 & 0xffffu) * 16 + lig];
        uint32_t u3 = hs[(size_t)(pk3 & 0xffffu) * 16 + lig];
        float c0 = bfhi(pk0), c1 = bfhi(pk1);
        float c2 = bfhi(pk2), c3 = bfhi(pk3);
        a0 = fmaf(c0, bflo(u0), a0); a1 = fmaf(c0, bfhi(u0), a1);
        a0 = fmaf(c1, bflo(u1), a0); a1 = fmaf(c1, bfhi(u1), a1);
        a0 = fmaf(c2, bflo(u2), a0); a1 = fmaf(c2, bfhi(u2), a1);
        a0 = fmaf(c3, bflo(u3), a0); a1 = fmaf(c3, bfhi(u3), a1);
    }
    if (i < e) {
        uint32_t pk0 = csr_pk[i];
        uint32_t pk1 = (i + 1 < e) ? csr_pk[i + 1] : 0u;   // coef +0 -> no-op
        uint32_t pk2 = (i + 2 < e) ? csr_pk[i + 2] : 0u;
        uint32_t u0 = hs[(size_t)(pk0 & 0xffffu) * 16 + lig];
        uint32_t u1 = hs[(size_t)(pk1 & 0xffffu) * 16 + lig];
        uint32_t u2 = hs[(size_t)(pk2 & 0xffffu) * 16 + lig];
        float c0 = bfhi(pk0), c1 = bfhi(pk1), c2 = bfhi(pk2);
        a0 = fmaf(c0, bflo(u0), a0); a1 = fmaf(c0, bfhi(u0), a1);
        a0 = fmaf(c1, bflo(u1), a0); a1 = fmaf(c1, bfhi(u1), a1);
        a0 = fmaf(c2, bflo(u2), a0); a1 = fmaf(c2, bfhi(u2), a1);
    }
    float dd = dis[node];
    uint32_t u = hs[(size_t)node * 16 + lig];
    float cs = dd * dd;
    int col = sl * 32 + lig * 2;
    a0 = fmaf(cs, bflo(u), a0) + bias[col];
    a1 = fmaf(cs, bfhi(u), a1) + bias[col + 1];
    *(float2*)(y + ((size_t)sl * n + node) * 32 + lig * 2) = make_float2(a0, a1);
}

// ------------------------------------------------------------ BN statistics
// y slice-major [S][n][32]; grid = (rowChunks, S)
__global__ __launch_bounds__(256) void colsum_kernel(
    const float* __restrict__ y, int n,
    float* __restrict__ sums, float* __restrict__ sumsq) {
    int sl = blockIdx.y;
    const float* ys = y + (size_t)sl * n * 32;
    int t = threadIdx.x, cg = t & 7, rt = t >> 3;
    float4 s = make_float4(0.f, 0.f, 0.f, 0.f);
    float4 q = make_float4(0.f, 0.f, 0.f, 0.f);
    for (int row = blockIdx.x * 32 + rt; row < n; row += gridDim.x * 32) {
        float4 v = *(const float4*)(ys + (size_t)row * 32 + cg * 4);
        s.x += v.x; s.y += v.y; s.z += v.z; s.w += v.w;
        q.x += v.x * v.x; q.y += v.y * v.y; q.z += v.z * v.z; q.w += v.w * v.w;
    }
    __shared__ float4 rs[32][8], rq[32][8];
    rs[rt][cg] = s; rq[rt][cg] = q;
    __syncthreads();
    for (int st = 16; st > 0; st >>= 1) {
        if (rt < st) {
            float4 o = rs[rt + st][cg], p = rq[rt + st][cg];
            rs[rt][cg].x += o.x; rs[rt][cg].y += o.y;
            rs[rt][cg].z += o.z; rs[rt][cg].w += o.w;
            rq[rt][cg].x += p.x; rq[rt][cg].y += p.y;
            rq[rt][cg].z += p.z; rq[rt][cg].w += p.w;
        }
        __syncthreads();
    }
    if (rt == 0) {
        float4 fs = rs[0][cg], fq = rq[0][cg];
        int col = sl * 32 + cg * 4;
        atomicAdd(&sums[col + 0], fs.x); atomicAdd(&sums[col + 1], fs.y);
        atomicAdd(&sums[col + 2], fs.z); atomicAdd(&sums[col + 3], fs.w);
        atomicAdd(&sumsq[col + 0], fq.x); atomicAdd(&sumsq[col + 1], fq.y);
        atomicAdd(&sumsq[col + 2], fq.z); atomicAdd(&sumsq[col + 3], fq.w);
    }
}

template <int F>
__global__ void finalize_kernel(const float* __restrict__ sums,
                                const float* __restrict__ sumsq,
                                const float* __restrict__ g, const float* __restrict__ be,
                                float* __restrict__ sc, float* __restrict__ sh, float n) {
    int c = threadIdx.x;
    if (c < F) {
        float m = sums[c] / n;
        float v = sumsq[c] / n - m * m;           // biased variance
        float r = rsqrtf(v + 1e-5f);
        float scale = r * g[c];
        sc[c] = scale;
        sh[c] = be[c] - m * scale;
    }
}

// ----------------------------------------------------------- final BN+ELU
// y slice-major [2][n][32] -> out row-major [n][64]
__global__ __launch_bounds__(256) void out_kernel(
    const float* __restrict__ y, const float* __restrict__ sc,
    const float* __restrict__ sh, float* __restrict__ out, int n) {
    int idx = blockIdx.x * 256 + threadIdx.x;
    if (idx >= n * 16) return;
    int node = idx >> 4, q = idx & 15;
    int sl = q >> 3, wq = (q & 7) * 4;
    int col = sl * 32 + wq;
    float4 v = *(const float4*)(y + ((size_t)sl * n + node) * 32 + wq);
    float4 s4 = *(const float4*)(sc + col);
    float4 h4 = *(const float4*)(sh + col);
    v.x = eluf(v.x * s4.x + h4.x);
    v.y = eluf(v.y * s4.y + h4.y);
    v.z = eluf(v.z * s4.z + h4.z);
    v.w = eluf(v.w * s4.w + h4.w);
    *(float4*)(out + (size_t)node * 64 + q * 4) = v;
}

// ---------------------------------------------------------------------------
extern "C" void kernel_launch(void* const* d_in, const int* in_sizes, int n_in,
                              void* d_out, int out_size, void* d_ws, size_t ws_size,
                              hipStream_t stream) {
    const float* x   = (const float*)d_in[0];
    const int*   edge = (const int*)d_in[1];
    const float* W0 = (const float*)d_in[2];
    const float* b0 = (const float*)d_in[3];
    const float* g0 = (const float*)d_in[4];
    const float* be0 = (const float*)d_in[5];
    const float* W1 = (const float*)d_in[6];
    const float* b1 = (const float*)d_in[7];
    const float* g1 = (const float*)d_in[8];
    const float* be1 = (const float*)d_in[9];
    const float* W2 = (const float*)d_in[10];
    const float* b2 = (const float*)d_in[11];
    const float* g2 = (const float*)d_in[12];
    const float* be2 = (const float*)d_in[13];

    const int n = in_sizes[0] / 128;     // 50000
    const int E = in_sizes[1] / 2;       // 1600000
    const int* esrc = edge;
    const int* edst = edge + E;

    const int NBUK = (n + 255) >> 8;               // 256-node buckets (<=256)
    const int EPC  = (E + NCH - 1) / NCH;          // edges per chunk

    char* w = (char*)d_ws;
    auto carve = [&](size_t bytes) -> void* {
        void* p = (void*)w;
        w += (bytes + 255) & ~(size_t)255;
        return p;
    };
    float*    y         = (float*)carve((size_t)n * 128 * 4);     // slice-major
    uint16_t* h         = (uint16_t*)carve((size_t)n * 128 * 2);  // slice-major
    uint32_t* csr_pk    = (uint32_t*)carve((size_t)E * 4);
    uint32_t* rec       = (uint32_t*)carve((size_t)E * 4);
    uint32_t* coarse    = (uint32_t*)carve((size_t)NBUK * NCH * 4);
    int*      beb       = (int*)carve((size_t)(NBUK + 1) * 4);
    int*      row_start = (int*)carve((size_t)(n + 1) * 4);
    float*    dis       = (float*)carve((size_t)n * 4);
    float*    sums      = (float*)carve(128 * 4);
    float*    sumsq     = (float*)carve(128 * 4);
    float*    sc        = (float*)carve(128 * 4);
    float*    sh        = (float*)carve(128 * 4);

    // ---- CSR build: counting sort + packed coef
    hist_coarse_kernel<<<NCH, 1024, 0, stream>>>(edst, coarse, E, EPC, NBUK);
    basescan_kernel<<<1, 1024, 0, stream>>>(coarse, beb, row_start, NBUK, E, n);
    partition_kernel<<<NCH, 1024, 0, stream>>>(esrc, edst, coarse, beb, rec, E, EPC, NBUK);
    fine_a_kernel<<<NBUK, 1024, 0, stream>>>(rec, beb, row_start, dis, n);
    fine_b_kernel<<<NBUK, 1024, 0, stream>>>(rec, beb, row_start, dis, csr_pk, n);

    const uint32_t* hp = (const uint32_t*)h;
    int gGemm  = (n + 127) / 128;
    int gGrp16 = (n + 15) / 16;          // blocks of 16 nodes

    // ---- layer 0 (in = x row-major, no BN on input)
    gemm_kernel<128, false, false><<<gGemm, 512, 0, stream>>>(x, W0, nullptr, nullptr, h, n);
    agg_sliced_kernel<4><<<gGrp16 * 4, 256, 0, stream>>>(hp, row_start, csr_pk, dis, b0, y, n);
    hipMemsetAsync(sums, 0, 128 * 4, stream);
    hipMemsetAsync(sumsq, 0, 128 * 4, stream);
    colsum_kernel<<<dim3(64, 4), 256, 0, stream>>>(y, n, sums, sumsq);
    finalize_kernel<128><<<1, 128, 0, stream>>>(sums, sumsq, g0, be0, sc, sh, (float)n);

    // ---- layer 1
    gemm_kernel<128, true, true><<<gGemm, 512, 0, stream>>>(y, W1, sc, sh, h, n);
    agg_sliced_kernel<4><<<gGrp16 * 4, 256, 0, stream>>>(hp, row_start, csr_pk, dis, b1, y, n);
    hipMemsetAsync(sums, 0, 128 * 4, stream);
    hipMemsetAsync(sumsq, 0, 128 * 4, stream);
    colsum_kernel<<<dim3(64, 4), 256, 0, stream>>>(y, n, sums, sumsq);
    finalize_kernel<128><<<1, 128, 0, stream>>>(sums, sumsq, g1, be1, sc, sh, (float)n);

    // ---- layer 2 (F=64 -> 2 slices)
    gemm_kernel<64, true, true><<<gGemm, 512, 0, stream>>>(y, W2, sc, sh, h, n);
    agg_sliced_kernel<2><<<gGrp16 * 2, 256, 0, stream>>>(hp, row_start, csr_pk, dis, b2, y, n);
    hipMemsetAsync(sums, 0, 64 * 4, stream);
    hipMemsetAsync(sumsq, 0, 64 * 4, stream);
    colsum_kernel<<<dim3(64, 2), 256, 0, stream>>>(y, n, sums, sumsq);
    finalize_kernel<64><<<1, 64, 0, stream>>>(sums, sumsq, g2, be2, sc, sh, (float)n);

    // ---- final BN2 + ELU -> out
    out_kernel<<<(n * 16 + 255) / 256, 256, 0, stream>>>(y, sc, sh, (float*)d_out, n);
}

// Round 11
// 459.659 us; speedup vs baseline: 1.2291x; 1.0202x over previous
//
#include <hip/hip_runtime.h>
#include <hip/hip_bf16.h>
#include <stdint.h>

// ---------------------------------------------------------------------------
// GNNEncoder: 3 x (GCNConv -> BatchNorm1d(train) -> ELU)
// N=50000, E=1.6M, dims 128->128->128->64
//
// R11: fatter per-lane agg payload.
//   Wave = 8 nodes x 8 lanes; lane owns uint2 (4 cols) of the 64B slice row
//   -> 1.75 wave-instr per node-edge (was 2.5), half the gathers (8B each),
//   pk loads broadcast over 8 lanes, no reduction, coalesced float4 store.
//   Slice-major h/y (S slices x 32 cols; 3.2MB slice pins in XCD L2).
//   GEMM xs pad BM+1; counting-sort build + packed bf16-coef CSR: unchanged.
// ---------------------------------------------------------------------------

#define NCH 256   // edge chunks (partition blocks)

static __device__ __forceinline__ float bflo(uint32_t u) {
    union { uint32_t u; float f; } x; x.u = u << 16; return x.f;
}
static __device__ __forceinline__ float bfhi(uint32_t u) {
    union { uint32_t u; float f; } x; x.u = u & 0xffff0000u; return x.f;
}
static __device__ __forceinline__ uint16_t f2bf(float f) {
    union { float f; uint32_t u; } x; x.f = f;
    uint32_t r = x.u + 0x7fffu + ((x.u >> 16) & 1u);   // RNE
    return (uint16_t)(r >> 16);
}
static __device__ __forceinline__ float eluf(float v) {
    return v > 0.f ? v : expm1f(v);
}

// --------------------------------------------- P1: coarse histogram
__global__ __launch_bounds__(1024) void hist_coarse_kernel(
    const int* __restrict__ dst, uint32_t* __restrict__ coarse,
    int E, int EPC, int NBUK) {
    __shared__ uint32_t cnt[256];
    int b = blockIdx.x, t = threadIdx.x;
    if (t < 256) cnt[t] = 0;
    __syncthreads();
    int e0 = b * EPC, e1 = min(E, e0 + EPC);
    for (int e = e0 + t; e < e1; e += 1024) atomicAdd(&cnt[dst[e] >> 8], 1u);
    __syncthreads();
    if (t < NBUK) coarse[(size_t)t * NCH + b] = cnt[t];
}

// --------------------------------------------- P2: base scan (1 block)
__global__ __launch_bounds__(1024) void basescan_kernel(
    uint32_t* __restrict__ coarse, int* __restrict__ beb,
    int* __restrict__ row_start, int NBUK, int E, int n) {
    __shared__ int btot[256];
    __shared__ int wt[4];
    int t = threadIdx.x;
    int sum = 0;
    if (t < NBUK) {
        uint32_t* rowp = coarse + (size_t)t * NCH;
        uint32_t run = 0;
        for (int ch = 0; ch < NCH; ++ch) {
            uint32_t v = rowp[ch];
            rowp[ch] = run;
            run += v;
        }
        sum = (int)run;
    }
    if (t < 256) btot[t] = (t < NBUK) ? sum : 0;
    __syncthreads();
    int x = 0, v = 0;
    if (t < 256) {
        int lane = t & 63, w = t >> 6;
        v = btot[t];
        x = v;
        #pragma unroll
        for (int off = 1; off < 64; off <<= 1) {
            int m = __shfl_up(x, off);
            if (lane >= off) x += m;
        }
        if (lane == 63) wt[w] = x;
    }
    __syncthreads();
    if (t < 256) {
        int w = t >> 6, woff = 0;
        for (int j = 0; j < w; ++j) woff += wt[j];
        int excl = woff + x - v;
        if (t < NBUK) beb[t] = excl;
    }
    if (t == 0) {
        beb[NBUK] = E;
        row_start[n] = E;
    }
}

// --------------------------------------------- P3: partition into buckets
// rec = (dst&255)<<16 | src   (n <= 65536)
__global__ __launch_bounds__(1024) void partition_kernel(
    const int* __restrict__ src, const int* __restrict__ dst,
    const uint32_t* __restrict__ coarse, const int* __restrict__ beb,
    uint32_t* __restrict__ rec, int E, int EPC, int NBUK) {
    __shared__ int cur[256];
    int b = blockIdx.x, t = threadIdx.x;
    if (t < NBUK) cur[t] = (int)coarse[(size_t)t * NCH + b] + beb[t];
    __syncthreads();
    int e0 = b * EPC, e1 = min(E, e0 + EPC);
    for (int e = e0 + t; e < e1; e += 1024) {
        int d = dst[e];
        int pos = atomicAdd(&cur[d >> 8], 1);
        rec[pos] = (uint32_t)src[e] | ((uint32_t)(d & 255) << 16);
    }
}

// --------------------------------------------- P4a: per-bucket hist -> row_start, dis
__global__ __launch_bounds__(1024) void fine_a_kernel(
    const uint32_t* __restrict__ rec, const int* __restrict__ beb,
    int* __restrict__ row_start, float* __restrict__ dis, int n) {
    __shared__ int cnt[256];
    __shared__ int wt[4];
    int b = blockIdx.x, t = threadIdx.x;
    int e0 = beb[b], e1 = beb[b + 1];
    if (t < 256) cnt[t] = 0;
    __syncthreads();
    for (int i = e0 + t; i < e1; i += 1024)
        atomicAdd(&cnt[(rec[i] >> 16) & 255], 1);
    __syncthreads();
    int x = 0, deg = 0;
    if (t < 256) {
        int lane = t & 63, w = t >> 6;
        deg = cnt[t];
        x = deg;
        #pragma unroll
        for (int off = 1; off < 64; off <<= 1) {
            int m = __shfl_up(x, off);
            if (lane >= off) x += m;
        }
        if (lane == 63) wt[w] = x;
    }
    __syncthreads();
    if (t < 256) {
        int w = t >> 6, woff = 0;
        for (int j = 0; j < w; ++j) woff += wt[j];
        int excl = woff + x - deg;
        int node = (b << 8) + t;
        if (node < n) {
            row_start[node] = e0 + excl;
            dis[node] = rsqrtf(1.0f + (float)deg);
        }
    }
}

// --------------------------------------------- P4b: packed csr placement
// csr_pk[pos] = bf16(dis[dst]*dis[src])<<16 | src
__global__ __launch_bounds__(1024) void fine_b_kernel(
    const uint32_t* __restrict__ rec, const int* __restrict__ beb,
    const int* __restrict__ row_start, const float* __restrict__ dis,
    uint32_t* __restrict__ csr_pk, int n) {
    __shared__ int cur[256];
    __shared__ float dloc[256];
    int b = blockIdx.x, t = threadIdx.x;
    int e0 = beb[b], e1 = beb[b + 1];
    if (t < 256) {
        int node = (b << 8) + t;
        cur[t] = (node < n) ? row_start[node] : 0;
        dloc[t] = (node < n) ? dis[node] : 0.f;
    }
    __syncthreads();
    for (int i = e0 + t; i < e1; i += 1024) {
        uint32_t r = rec[i];
        int s = (int)(r & 0xffffu);
        int dl = (int)((r >> 16) & 255u);
        float c = dloc[dl] * dis[s];
        int pos = atomicAdd(&cur[dl], 1);
        csr_pk[pos] = ((uint32_t)f2bf(c) << 16) | (uint32_t)s;
    }
}

// ------------------------------------------------------------------- GEMM
// h (bf16, slice-major [F/32][n][32]) = act(in)[n][128] @ W[128][F]
// in: row-major [n][128] (layer 0) or slice-major [4][n][32] (layers 1,2).
template <int F, bool BN, bool SLICED_IN>
__global__ __launch_bounds__(512) void gemm_kernel(
    const float* __restrict__ in, const float* __restrict__ W,
    const float* __restrict__ sc, const float* __restrict__ sh,
    uint16_t* __restrict__ h, int n) {
    constexpr int K = 128;
    constexpr int BM = 128;
    __shared__ float xs[K][BM + 1];   // stride 129: 4-way conflict on write phase
    __shared__ float ws[K][F];
    int t = threadIdx.x;
    int row0 = blockIdx.x * BM;

    for (int i = t * 4; i < K * F; i += 512 * 4) {
        *(float4*)((float*)ws + i) = *(const float4*)(W + i);
    }
    for (int idx = t; idx < BM * K / 4; idx += 512) {
        int r = idx >> 5;
        int k4 = (idx & 31) << 2;
        int gr = row0 + r;
        float4 v = make_float4(0.f, 0.f, 0.f, 0.f);
        if (gr < n) {
            const float* p;
            if (SLICED_IN)
                p = in + ((size_t)(k4 >> 5) * n + gr) * 32 + (k4 & 31);
            else
                p = in + (size_t)gr * K + k4;
            v = *(const float4*)p;
        }
        if (BN) {
            float4 s4 = *(const float4*)(sc + k4);
            float4 h4 = *(const float4*)(sh + k4);
            v.x = eluf(v.x * s4.x + h4.x);
            v.y = eluf(v.y * s4.y + h4.y);
            v.z = eluf(v.z * s4.z + h4.z);
            v.w = eluf(v.w * s4.w + h4.w);
        }
        xs[k4 + 0][r] = v.x;
        xs[k4 + 1][r] = v.y;
        xs[k4 + 2][r] = v.z;
        xs[k4 + 3][r] = v.w;
    }
    __syncthreads();

    constexpr int CW = F / 16;
    int tx = t & 15;
    int ty = t >> 4;
    float acc[4][CW];
    #pragma unroll
    for (int r = 0; r < 4; ++r)
        #pragma unroll
        for (int c = 0; c < CW; ++c) acc[r][c] = 0.f;

    for (int k = 0; k < K; ++k) {
        float4 xv = *(const float4*)&xs[k][ty * 4];
        float wv[CW];
        *(float4*)wv = *(const float4*)&ws[k][tx * CW];
        if (CW == 8) *(float4*)(wv + 4) = *(const float4*)&ws[k][tx * CW + 4];
        const float* xp = &xv.x;
        #pragma unroll
        for (int r = 0; r < 4; ++r)
            #pragma unroll
            for (int c = 0; c < CW; ++c)
                acc[r][c] = fmaf(xp[r], wv[c], acc[r][c]);
    }

    int col0 = tx * CW;
    int sl = col0 >> 5, off = col0 & 31;
    #pragma unroll
    for (int r = 0; r < 4; ++r) {
        int row = row0 + ty * 4 + r;
        if (row < n) {
            uint16_t* dstp = h + ((size_t)sl * n + row) * 32 + off;
            uint32_t p[CW / 2];
            #pragma unroll
            for (int c = 0; c < CW; c += 2)
                p[c / 2] = (uint32_t)f2bf(acc[r][c]) | ((uint32_t)f2bf(acc[r][c + 1]) << 16);
            if (CW == 8) *(uint4*)dstp = make_uint4(p[0], p[1], p[2], p[3]);
            else         *(uint2*)dstp = make_uint2(p[0], p[1]);
        }
    }
}

// -------------------------------------------------------------------- AGG
// Wave = 8 nodes x 8 lanes; lane owns uint2 (4 cols) of the 64B slice row.
// Unroll-4 packed-CSR: 4 pk loads + 4 uint2 gathers in flight; no cross-lane
// reduction; coalesced float4 store. Slice-major h [S][n][16 u32],
// y [S][n][32 f32]; slice = bid & (S-1) -> XCD round-robin pins slices.
template <int S>
__global__ __launch_bounds__(256) void agg_sliced_kernel(
    const uint32_t* __restrict__ hp,
    const int* __restrict__ row_start, const uint32_t* __restrict__ csr_pk,
    const float* __restrict__ dis, const float* __restrict__ bias,
    float* __restrict__ y, int n) {
    int bid = blockIdx.x;
    int sl = bid & (S - 1);
    int grp = bid / S;                 // 32-node group
    int wv = threadIdx.x >> 6;
    int lane = threadIdx.x & 63;
    int ng = lane >> 3;                // node within wave (0..7)
    int lig = lane & 7;                // uint2 index (4 cols)
    int node = grp * 32 + wv * 8 + ng;
    if (node >= n) return;
    int s = row_start[node], e = row_start[node + 1];
    const uint2* hs = (const uint2*)(hp + (size_t)sl * n * 16);
    float a0 = 0.f, a1 = 0.f, a2 = 0.f, a3 = 0.f;
    int i = s;
    for (; i + 4 <= e; i += 4) {
        uint32_t p0 = csr_pk[i];
        uint32_t p1 = csr_pk[i + 1];
        uint32_t p2 = csr_pk[i + 2];
        uint32_t p3 = csr_pk[i + 3];
        uint2 u0 = hs[(size_t)(p0 & 0xffffu) * 8 + lig];
        uint2 u1 = hs[(size_t)(p1 & 0xffffu) * 8 + lig];
        uint2 u2 = hs[(size_t)(p2 & 0xffffu) * 8 + lig];
        uint2 u3 = hs[(size_t)(p3 & 0xffffu) * 8 + lig];
        float c0 = bfhi(p0), c1 = bfhi(p1), c2 = bfhi(p2), c3 = bfhi(p3);
        a0 = fmaf(c0, bflo(u0.x), a0); a1 = fmaf(c0, bfhi(u0.x), a1);
        a2 = fmaf(c0, bflo(u0.y), a2); a3 = fmaf(c0, bfhi(u0.y), a3);
        a0 = fmaf(c1, bflo(u1.x), a0); a1 = fmaf(c1, bfhi(u1.x), a1);
        a2 = fmaf(c1, bflo(u1.y), a2); a3 = fmaf(c1, bfhi(u1.y), a3);
        a0 = fmaf(c2, bflo(u2.x), a0); a1 = fmaf(c2, bfhi(u2.x), a1);
        a2 = fmaf(c2, bflo(u2.y), a2); a3 = fmaf(c2, bfhi(u2.y), a3);
        a0 = fmaf(c3, bflo(u3.x), a0); a1 = fmaf(c3, bfhi(u3.x), a1);
        a2 = fmaf(c3, bflo(u3.y), a2); a3 = fmaf(c3, bfhi(u3.y), a3);
    }
    for (; i < e; ++i) {
        uint32_t p = csr_pk[i];
        uint2 u = hs[(size_t)(p & 0xffffu) * 8 + lig];
        float c = bfhi(p);
        a0 = fmaf(c, bflo(u.x), a0); a1 = fmaf(c, bfhi(u.x), a1);
        a2 = fmaf(c, bflo(u.y), a2); a3 = fmaf(c, bfhi(u.y), a3);
    }
    float dd = dis[node];
    uint2 u = hs[(size_t)node * 8 + lig];
    float cs = dd * dd;
    int col = sl * 32 + lig * 4;
    a0 = fmaf(cs, bflo(u.x), a0) + bias[col];
    a1 = fmaf(cs, bfhi(u.x), a1) + bias[col + 1];
    a2 = fmaf(cs, bflo(u.y), a2) + bias[col + 2];
    a3 = fmaf(cs, bfhi(u.y), a3) + bias[col + 3];
    *(float4*)(y + ((size_t)sl * n + node) * 32 + lig * 4) = make_float4(a0, a1, a2, a3);
}

// ------------------------------------------------------------ BN statistics
// y slice-major [S][n][32]; grid = (rowChunks, S)
__global__ __launch_bounds__(256) void colsum_kernel(
    const float* __restrict__ y, int n,
    float* __restrict__ sums, float* __restrict__ sumsq) {
    int sl = blockIdx.y;
    const float* ys = y + (size_t)sl * n * 32;
    int t = threadIdx.x, cg = t & 7, rt = t >> 3;
    float4 s = make_float4(0.f, 0.f, 0.f, 0.f);
    float4 q = make_float4(0.f, 0.f, 0.f, 0.f);
    for (int row = blockIdx.x * 32 + rt; row < n; row += gridDim.x * 32) {
        float4 v = *(const float4*)(ys + (size_t)row * 32 + cg * 4);
        s.x += v.x; s.y += v.y; s.z += v.z; s.w += v.w;
        q.x += v.x * v.x; q.y += v.y * v.y; q.z += v.z * v.z; q.w += v.w * v.w;
    }
    __shared__ float4 rs[32][8], rq[32][8];
    rs[rt][cg] = s; rq[rt][cg] = q;
    __syncthreads();
    for (int st = 16; st > 0; st >>= 1) {
        if (rt < st) {
            float4 o = rs[rt + st][cg], p = rq[rt + st][cg];
            rs[rt][cg].x += o.x; rs[rt][cg].y += o.y;
            rs[rt][cg].z += o.z; rs[rt][cg].w += o.w;
            rq[rt][cg].x += p.x; rq[rt][cg].y += p.y;
            rq[rt][cg].z += p.z; rq[rt][cg].w += p.w;
        }
        __syncthreads();
    }
    if (rt == 0) {
        float4 fs = rs[0][cg], fq = rq[0][cg];
        int col = sl * 32 + cg * 4;
        atomicAdd(&sums[col + 0], fs.x); atomicAdd(&sums[col + 1], fs.y);
        atomicAdd(&sums[col + 2], fs.z); atomicAdd(&sums[col + 3], fs.w);
        atomicAdd(&sumsq[col + 0], fq.x); atomicAdd(&sumsq[col + 1], fq.y);
        atomicAdd(&sumsq[col + 2], fq.z); atomicAdd(&sumsq[col + 3], fq.w);
    }
}

template <int F>
__global__ void finalize_kernel(const float* __restrict__ sums,
                                const float* __restrict__ sumsq,
                                const float* __restrict__ g, const float* __restrict__ be,
                                float* __restrict__ sc, float* __restrict__ sh, float n) {
    int c = threadIdx.x;
    if (c < F) {
        float m = sums[c] / n;
        float v = sumsq[c] / n - m * m;           // biased variance
        float r = rsqrtf(v + 1e-5f);
        float scale = r * g[c];
        sc[c] = scale;
        sh[c] = be[c] - m * scale;
    }
}

// ----------------------------------------------------------- final BN+ELU
// y slice-major [2][n][32] -> out row-major [n][64]
__global__ __launch_bounds__(256) void out_kernel(
    const float* __restrict__ y, const float* __restrict__ sc,
    const float* __restrict__ sh, float* __restrict__ out, int n) {
    int idx = blockIdx.x * 256 + threadIdx.x;
    if (idx >= n * 16) return;
    int node = idx >> 4, q = idx & 15;
    int sl = q >> 3, wq = (q & 7) * 4;
    int col = sl * 32 + wq;
    float4 v = *(const float4*)(y + ((size_t)sl * n + node) * 32 + wq);
    float4 s4 = *(const float4*)(sc + col);
    float4 h4 = *(const float4*)(sh + col);
    v.x = eluf(v.x * s4.x + h4.x);
    v.y = eluf(v.y * s4.y + h4.y);
    v.z = eluf(v.z * s4.z + h4.z);
    v.w = eluf(v.w * s4.w + h4.w);
    *(float4*)(out + (size_t)node * 64 + q * 4) = v;
}

// ---------------------------------------------------------------------------
extern "C" void kernel_launch(void* const* d_in, const int* in_sizes, int n_in,
                              void* d_out, int out_size, void* d_ws, size_t ws_size,
                              hipStream_t stream) {
    const float* x   = (const float*)d_in[0];
    const int*   edge = (const int*)d_in[1];
    const float* W0 = (const float*)d_in[2];
    const float* b0 = (const float*)d_in[3];
    const float* g0 = (const float*)d_in[4];
    const float* be0 = (const float*)d_in[5];
    const float* W1 = (const float*)d_in[6];
    const float* b1 = (const float*)d_in[7];
    const float* g1 = (const float*)d_in[8];
    const float* be1 = (const float*)d_in[9];
    const float* W2 = (const float*)d_in[10];
    const float* b2 = (const float*)d_in[11];
    const float* g2 = (const float*)d_in[12];
    const float* be2 = (const float*)d_in[13];

    const int n = in_sizes[0] / 128;     // 50000
    const int E = in_sizes[1] / 2;       // 1600000
    const int* esrc = edge;
    const int* edst = edge + E;

    const int NBUK = (n + 255) >> 8;               // 256-node buckets (<=256)
    const int EPC  = (E + NCH - 1) / NCH;          // edges per chunk

    char* w = (char*)d_ws;
    auto carve = [&](size_t bytes) -> void* {
        void* p = (void*)w;
        w += (bytes + 255) & ~(size_t)255;
        return p;
    };
    float*    y         = (float*)carve((size_t)n * 128 * 4);     // slice-major
    uint16_t* h         = (uint16_t*)carve((size_t)n * 128 * 2);  // slice-major
    uint32_t* csr_pk    = (uint32_t*)carve((size_t)E * 4);
    uint32_t* rec       = (uint32_t*)carve((size_t)E * 4);
    uint32_t* coarse    = (uint32_t*)carve((size_t)NBUK * NCH * 4);
    int*      beb       = (int*)carve((size_t)(NBUK + 1) * 4);
    int*      row_start = (int*)carve((size_t)(n + 1) * 4);
    float*    dis       = (float*)carve((size_t)n * 4);
    float*    sums      = (float*)carve(128 * 4);
    float*    sumsq     = (float*)carve(128 * 4);
    float*    sc        = (float*)carve(128 * 4);
    float*    sh        = (float*)carve(128 * 4);

    // ---- CSR build: counting sort + packed coef
    hist_coarse_kernel<<<NCH, 1024, 0, stream>>>(edst, coarse, E, EPC, NBUK);
    basescan_kernel<<<1, 1024, 0, stream>>>(coarse, beb, row_start, NBUK, E, n);
    partition_kernel<<<NCH, 1024, 0, stream>>>(esrc, edst, coarse, beb, rec, E, EPC, NBUK);
    fine_a_kernel<<<NBUK, 1024, 0, stream>>>(rec, beb, row_start, dis, n);
    fine_b_kernel<<<NBUK, 1024, 0, stream>>>(rec, beb, row_start, dis, csr_pk, n);

    const uint32_t* hp = (const uint32_t*)h;
    int gGemm  = (n + 127) / 128;
    int gGrp32 = (n + 31) / 32;          // blocks of 32 nodes

    // ---- layer 0 (in = x row-major, no BN on input)
    gemm_kernel<128, false, false><<<gGemm, 512, 0, stream>>>(x, W0, nullptr, nullptr, h, n);
    agg_sliced_kernel<4><<<gGrp32 * 4, 256, 0, stream>>>(hp, row_start, csr_pk, dis, b0, y, n);
    hipMemsetAsync(sums, 0, 128 * 4, stream);
    hipMemsetAsync(sumsq, 0, 128 * 4, stream);
    colsum_kernel<<<dim3(64, 4), 256, 0, stream>>>(y, n, sums, sumsq);
    finalize_kernel<128><<<1, 128, 0, stream>>>(sums, sumsq, g0, be0, sc, sh, (float)n);

    // ---- layer 1
    gemm_kernel<128, true, true><<<gGemm, 512, 0, stream>>>(y, W1, sc, sh, h, n);
    agg_sliced_kernel<4><<<gGrp32 * 4, 256, 0, stream>>>(hp, row_start, csr_pk, dis, b1, y, n);
    hipMemsetAsync(sums, 0, 128 * 4, stream);
    hipMemsetAsync(sumsq, 0, 128 * 4, stream);
    colsum_kernel<<<dim3(64, 4), 256, 0, stream>>>(y, n, sums, sumsq);
    finalize_kernel<128><<<1, 128, 0, stream>>>(sums, sumsq, g1, be1, sc, sh, (float)n);

    // ---- layer 2 (F=64 -> 2 slices)
    gemm_kernel<64, true, true><<<gGemm, 512, 0, stream>>>(y, W2, sc, sh, h, n);
    agg_sliced_kernel<2><<<gGrp32 * 2, 256, 0, stream>>>(hp, row_start, csr_pk, dis, b2, y, n);
    hipMemsetAsync(sums, 0, 64 * 4, stream);
    hipMemsetAsync(sumsq, 0, 64 * 4, stream);
    colsum_kernel<<<dim3(64, 2), 256, 0, stream>>>(y, n, sums, sumsq);
    finalize_kernel<64><<<1, 64, 0, stream>>>(sums, sumsq, g2, be2, sc, sh, (float)n);

    // ---- final BN2 + ELU -> out
    out_kernel<<<(n * 16 + 255) / 256, 256, 0, stream>>>(y, sc, sh, (float*)d_out, n);
}

// Round 13
// 458.066 us; speedup vs baseline: 1.2334x; 1.0035x over previous
//
#include <hip/hip_runtime.h>
#include <hip/hip_bf16.h>
#include <stdint.h>

// ---------------------------------------------------------------------------
// GNNEncoder: 3 x (GCNConv -> BatchNorm1d(train) -> ELU)
// N=50000, E=1.6M, dims 128->128->128->64
//
// R13 = R12 resubmitted (GPU acquisition timed out; no measurement).
// R12:
//  - agg: unroll-8 + single pk=0-padded tail (pads gather L1-hot row 0).
//  - gemm F=128: bf16 LDS tiles (66KB -> 2 blocks/CU), 256 thr x (8x8) reg
//    blocking -> 2 ds_read_b128 per 64 FMA (VALU-bound ~13us, was ~23).
//  - finalize zeroes sums/sumsq (drops 4 memset dispatches).
//  Slice-major h/y, packed bf16-coef CSR, counting-sort build: unchanged.
// ---------------------------------------------------------------------------

#define NCH 256   // edge chunks (partition blocks)

static __device__ __forceinline__ float bflo(uint32_t u) {
    union { uint32_t u; float f; } x; x.u = u << 16; return x.f;
}
static __device__ __forceinline__ float bfhi(uint32_t u) {
    union { uint32_t u; float f; } x; x.u = u & 0xffff0000u; return x.f;
}
static __device__ __forceinline__ uint16_t f2bf(float f) {
    union { float f; uint32_t u; } x; x.f = f;
    uint32_t r = x.u + 0x7fffu + ((x.u >> 16) & 1u);   // RNE
    return (uint16_t)(r >> 16);
}
static __device__ __forceinline__ float eluf(float v) {
    return v > 0.f ? v : expm1f(v);
}

// --------------------------------------------- P1: coarse histogram
__global__ __launch_bounds__(1024) void hist_coarse_kernel(
    const int* __restrict__ dst, uint32_t* __restrict__ coarse,
    int E, int EPC, int NBUK) {
    __shared__ uint32_t cnt[256];
    int b = blockIdx.x, t = threadIdx.x;
    if (t < 256) cnt[t] = 0;
    __syncthreads();
    int e0 = b * EPC, e1 = min(E, e0 + EPC);
    for (int e = e0 + t; e < e1; e += 1024) atomicAdd(&cnt[dst[e] >> 8], 1u);
    __syncthreads();
    if (t < NBUK) coarse[(size_t)t * NCH + b] = cnt[t];
}

// --------------------------------------------- P2: base scan (1 block)
__global__ __launch_bounds__(1024) void basescan_kernel(
    uint32_t* __restrict__ coarse, int* __restrict__ beb,
    int* __restrict__ row_start, int NBUK, int E, int n) {
    __shared__ int btot[256];
    __shared__ int wt[4];
    int t = threadIdx.x;
    int sum = 0;
    if (t < NBUK) {
        uint32_t* rowp = coarse + (size_t)t * NCH;
        uint32_t run = 0;
        for (int ch = 0; ch < NCH; ++ch) {
            uint32_t v = rowp[ch];
            rowp[ch] = run;
            run += v;
        }
        sum = (int)run;
    }
    if (t < 256) btot[t] = (t < NBUK) ? sum : 0;
    __syncthreads();
    int x = 0, v = 0;
    if (t < 256) {
        int lane = t & 63, w = t >> 6;
        v = btot[t];
        x = v;
        #pragma unroll
        for (int off = 1; off < 64; off <<= 1) {
            int m = __shfl_up(x, off);
            if (lane >= off) x += m;
        }
        if (lane == 63) wt[w] = x;
    }
    __syncthreads();
    if (t < 256) {
        int w = t >> 6, woff = 0;
        for (int j = 0; j < w; ++j) woff += wt[j];
        int excl = woff + x - v;
        if (t < NBUK) beb[t] = excl;
    }
    if (t == 0) {
        beb[NBUK] = E;
        row_start[n] = E;
    }
}

// --------------------------------------------- P3: partition into buckets
// rec = (dst&255)<<16 | src   (n <= 65536)
__global__ __launch_bounds__(1024) void partition_kernel(
    const int* __restrict__ src, const int* __restrict__ dst,
    const uint32_t* __restrict__ coarse, const int* __restrict__ beb,
    uint32_t* __restrict__ rec, int E, int EPC, int NBUK) {
    __shared__ int cur[256];
    int b = blockIdx.x, t = threadIdx.x;
    if (t < NBUK) cur[t] = (int)coarse[(size_t)t * NCH + b] + beb[t];
    __syncthreads();
    int e0 = b * EPC, e1 = min(E, e0 + EPC);
    for (int e = e0 + t; e < e1; e += 1024) {
        int d = dst[e];
        int pos = atomicAdd(&cur[d >> 8], 1);
        rec[pos] = (uint32_t)src[e] | ((uint32_t)(d & 255) << 16);
    }
}

// --------------------------------------------- P4a: per-bucket hist -> row_start, dis
__global__ __launch_bounds__(1024) void fine_a_kernel(
    const uint32_t* __restrict__ rec, const int* __restrict__ beb,
    int* __restrict__ row_start, float* __restrict__ dis, int n) {
    __shared__ int cnt[256];
    __shared__ int wt[4];
    int b = blockIdx.x, t = threadIdx.x;
    int e0 = beb[b], e1 = beb[b + 1];
    if (t < 256) cnt[t] = 0;
    __syncthreads();
    for (int i = e0 + t; i < e1; i += 1024)
        atomicAdd(&cnt[(rec[i] >> 16) & 255], 1);
    __syncthreads();
    int x = 0, deg = 0;
    if (t < 256) {
        int lane = t & 63, w = t >> 6;
        deg = cnt[t];
        x = deg;
        #pragma unroll
        for (int off = 1; off < 64; off <<= 1) {
            int m = __shfl_up(x, off);
            if (lane >= off) x += m;
        }
        if (lane == 63) wt[w] = x;
    }
    __syncthreads();
    if (t < 256) {
        int w = t >> 6, woff = 0;
        for (int j = 0; j < w; ++j) woff += wt[j];
        int excl = woff + x - deg;
        int node = (b << 8) + t;
        if (node < n) {
            row_start[node] = e0 + excl;
            dis[node] = rsqrtf(1.0f + (float)deg);
        }
    }
}

// --------------------------------------------- P4b: packed csr placement
// csr_pk[pos] = bf16(dis[dst]*dis[src])<<16 | src
__global__ __launch_bounds__(1024) void fine_b_kernel(
    const uint32_t* __restrict__ rec, const int* __restrict__ beb,
    const int* __restrict__ row_start, const float* __restrict__ dis,
    uint32_t* __restrict__ csr_pk, int n) {
    __shared__ int cur[256];
    __shared__ float dloc[256];
    int b = blockIdx.x, t = threadIdx.x;
    int e0 = beb[b], e1 = beb[b + 1];
    if (t < 256) {
        int node = (b << 8) + t;
        cur[t] = (node < n) ? row_start[node] : 0;
        dloc[t] = (node < n) ? dis[node] : 0.f;
    }
    __syncthreads();
    for (int i = e0 + t; i < e1; i += 1024) {
        uint32_t r = rec[i];
        int s = (int)(r & 0xffffu);
        int dl = (int)((r >> 16) & 255u);
        float c = dloc[dl] * dis[s];
        int pos = atomicAdd(&cur[dl], 1);
        csr_pk[pos] = ((uint32_t)f2bf(c) << 16) | (uint32_t)s;
    }
}

// -------------------------------------------------------- GEMM F=128 (bf16 LDS)
// h (bf16, slice-major [4][n][32]) = act(in)[n][128] @ W[128][128]
// 256 threads; thread = 8 rows x 8 cols; per k: 2 ds_read_b128 for 64 FMA.
template <bool BN, bool SLICED_IN>
__global__ __launch_bounds__(256) void gemm128_kernel(
    const float* __restrict__ in, const float* __restrict__ W,
    const float* __restrict__ sc, const float* __restrict__ sh,
    uint16_t* __restrict__ h, int n) {
    constexpr int K = 128;
    constexpr int BM = 128;
    __shared__ uint16_t xs[K][BM + 8];   // bf16, row stride 272B (16B-aligned)
    __shared__ uint16_t ws[K][128 + 8];
    int t = threadIdx.x;
    int row0 = blockIdx.x * BM;

    // stage W (f32 -> bf16)
    for (int i = t * 4; i < K * 128; i += 256 * 4) {
        float4 v = *(const float4*)(W + i);
        int k = i >> 7, c = i & 127;
        ws[k][c + 0] = f2bf(v.x);
        ws[k][c + 1] = f2bf(v.y);
        ws[k][c + 2] = f2bf(v.z);
        ws[k][c + 3] = f2bf(v.w);
    }
    // stage x tile (BN+ELU fused), transposed, bf16
    for (int idx = t; idx < BM * K / 4; idx += 256) {
        int r = idx >> 5;
        int k4 = (idx & 31) << 2;
        int gr = row0 + r;
        float4 v = make_float4(0.f, 0.f, 0.f, 0.f);
        if (gr < n) {
            const float* p;
            if (SLICED_IN)
                p = in + ((size_t)(k4 >> 5) * n + gr) * 32 + (k4 & 31);
            else
                p = in + (size_t)gr * K + k4;
            v = *(const float4*)p;
        }
        if (BN) {
            float4 s4 = *(const float4*)(sc + k4);
            float4 h4 = *(const float4*)(sh + k4);
            v.x = eluf(v.x * s4.x + h4.x);
            v.y = eluf(v.y * s4.y + h4.y);
            v.z = eluf(v.z * s4.z + h4.z);
            v.w = eluf(v.w * s4.w + h4.w);
        }
        xs[k4 + 0][r] = f2bf(v.x);
        xs[k4 + 1][r] = f2bf(v.y);
        xs[k4 + 2][r] = f2bf(v.z);
        xs[k4 + 3][r] = f2bf(v.w);
    }
    __syncthreads();

    int tx = t & 15;                     // col group (8 cols)
    int ty = t >> 4;                     // row group (8 rows)
    float acc[8][8];
    #pragma unroll
    for (int r = 0; r < 8; ++r)
        #pragma unroll
        for (int c = 0; c < 8; ++c) acc[r][c] = 0.f;

    for (int k = 0; k < K; ++k) {
        uint4 xu = *(const uint4*)&xs[k][ty * 8];
        uint4 wu = *(const uint4*)&ws[k][tx * 8];
        float xr[8], wc[8];
        xr[0] = bflo(xu.x); xr[1] = bfhi(xu.x);
        xr[2] = bflo(xu.y); xr[3] = bfhi(xu.y);
        xr[4] = bflo(xu.z); xr[5] = bfhi(xu.z);
        xr[6] = bflo(xu.w); xr[7] = bfhi(xu.w);
        wc[0] = bflo(wu.x); wc[1] = bfhi(wu.x);
        wc[2] = bflo(wu.y); wc[3] = bfhi(wu.y);
        wc[4] = bflo(wu.z); wc[5] = bfhi(wu.z);
        wc[6] = bflo(wu.w); wc[7] = bfhi(wu.w);
        #pragma unroll
        for (int r = 0; r < 8; ++r)
            #pragma unroll
            for (int c = 0; c < 8; ++c)
                acc[r][c] = fmaf(xr[r], wc[c], acc[r][c]);
    }

    int col0 = tx * 8;
    int sl = col0 >> 5, off = col0 & 31;
    #pragma unroll
    for (int r = 0; r < 8; ++r) {
        int row = row0 + ty * 8 + r;
        if (row < n) {
            uint16_t* dstp = h + ((size_t)sl * n + row) * 32 + off;
            uint32_t p[4];
            #pragma unroll
            for (int c = 0; c < 8; c += 2)
                p[c / 2] = (uint32_t)f2bf(acc[r][c]) | ((uint32_t)f2bf(acc[r][c + 1]) << 16);
            *(uint4*)dstp = make_uint4(p[0], p[1], p[2], p[3]);
        }
    }
}

// ------------------------------------------------------------- GEMM F=64 (f32)
// h (bf16, slice-major [2][n][32]) = act(in)[n][128] @ W[128][64]
template <int F, bool BN, bool SLICED_IN>
__global__ __launch_bounds__(512) void gemm_kernel(
    const float* __restrict__ in, const float* __restrict__ W,
    const float* __restrict__ sc, const float* __restrict__ sh,
    uint16_t* __restrict__ h, int n) {
    constexpr int K = 128;
    constexpr int BM = 128;
    __shared__ float xs[K][BM + 1];
    __shared__ float ws[K][F];
    int t = threadIdx.x;
    int row0 = blockIdx.x * BM;

    for (int i = t * 4; i < K * F; i += 512 * 4) {
        *(float4*)((float*)ws + i) = *(const float4*)(W + i);
    }
    for (int idx = t; idx < BM * K / 4; idx += 512) {
        int r = idx >> 5;
        int k4 = (idx & 31) << 2;
        int gr = row0 + r;
        float4 v = make_float4(0.f, 0.f, 0.f, 0.f);
        if (gr < n) {
            const float* p;
            if (SLICED_IN)
                p = in + ((size_t)(k4 >> 5) * n + gr) * 32 + (k4 & 31);
            else
                p = in + (size_t)gr * K + k4;
            v = *(const float4*)p;
        }
        if (BN) {
            float4 s4 = *(const float4*)(sc + k4);
            float4 h4 = *(const float4*)(sh + k4);
            v.x = eluf(v.x * s4.x + h4.x);
            v.y = eluf(v.y * s4.y + h4.y);
            v.z = eluf(v.z * s4.z + h4.z);
            v.w = eluf(v.w * s4.w + h4.w);
        }
        xs[k4 + 0][r] = v.x;
        xs[k4 + 1][r] = v.y;
        xs[k4 + 2][r] = v.z;
        xs[k4 + 3][r] = v.w;
    }
    __syncthreads();

    constexpr int CW = F / 16;           // 4
    int tx = t & 15;
    int ty = t >> 4;
    float acc[4][CW];
    #pragma unroll
    for (int r = 0; r < 4; ++r)
        #pragma unroll
        for (int c = 0; c < CW; ++c) acc[r][c] = 0.f;

    for (int k = 0; k < K; ++k) {
        float4 xv = *(const float4*)&xs[k][ty * 4];
        float wv[CW];
        *(float4*)wv = *(const float4*)&ws[k][tx * CW];
        const float* xp = &xv.x;
        #pragma unroll
        for (int r = 0; r < 4; ++r)
            #pragma unroll
            for (int c = 0; c < CW; ++c)
                acc[r][c] = fmaf(xp[r], wv[c], acc[r][c]);
    }

    int col0 = tx * CW;
    int sl = col0 >> 5, off = col0 & 31;
    #pragma unroll
    for (int r = 0; r < 4; ++r) {
        int row = row0 + ty * 4 + r;
        if (row < n) {
            uint16_t* dstp = h + ((size_t)sl * n + row) * 32 + off;
            uint32_t p[CW / 2];
            #pragma unroll
            for (int c = 0; c < CW; c += 2)
                p[c / 2] = (uint32_t)f2bf(acc[r][c]) | ((uint32_t)f2bf(acc[r][c + 1]) << 16);
            *(uint2*)dstp = make_uint2(p[0], p[1]);
        }
    }
}

// -------------------------------------------------------------------- AGG
// Wave = 8 nodes x 8 lanes; lane owns uint2 (4 cols) of the 64B slice row.
// Unroll-8 + single pk=0-padded tail (pad gathers hit L1-hot row 0).
template <int S>
__global__ __launch_bounds__(256) void agg_sliced_kernel(
    const uint32_t* __restrict__ hp,
    const int* __restrict__ row_start, const uint32_t* __restrict__ csr_pk,
    const float* __restrict__ dis, const float* __restrict__ bias,
    float* __restrict__ y, int n) {
    int bid = blockIdx.x;
    int sl = bid & (S - 1);
    int grp = bid / S;                 // 32-node group
    int wv = threadIdx.x >> 6;
    int lane = threadIdx.x & 63;
    int ng = lane >> 3;                // node within wave (0..7)
    int lig = lane & 7;                // uint2 index (4 cols)
    int node = grp * 32 + wv * 8 + ng;
    if (node >= n) return;
    int s = row_start[node], e = row_start[node + 1];
    const uint2* hs = (const uint2*)(hp + (size_t)sl * n * 16);
    float a0 = 0.f, a1 = 0.f, a2 = 0.f, a3 = 0.f;
    int i = s;
    for (; i + 8 <= e; i += 8) {
        uint32_t p[8];
        #pragma unroll
        for (int j = 0; j < 8; ++j) p[j] = csr_pk[i + j];
        uint2 u[8];
        #pragma unroll
        for (int j = 0; j < 8; ++j) u[j] = hs[(size_t)(p[j] & 0xffffu) * 8 + lig];
        #pragma unroll
        for (int j = 0; j < 8; ++j) {
            float c = bfhi(p[j]);
            a0 = fmaf(c, bflo(u[j].x), a0); a1 = fmaf(c, bfhi(u[j].x), a1);
            a2 = fmaf(c, bflo(u[j].y), a2); a3 = fmaf(c, bfhi(u[j].y), a3);
        }
    }
    if (i < e) {
        uint32_t p[8];
        #pragma unroll
        for (int j = 0; j < 8; ++j) p[j] = (i + j < e) ? csr_pk[i + j] : 0u;
        uint2 u[8];
        #pragma unroll
        for (int j = 0; j < 8; ++j) u[j] = hs[(size_t)(p[j] & 0xffffu) * 8 + lig];
        #pragma unroll
        for (int j = 0; j < 8; ++j) {
            float c = bfhi(p[j]);               // 0 for pads
            a0 = fmaf(c, bflo(u[j].x), a0); a1 = fmaf(c, bfhi(u[j].x), a1);
            a2 = fmaf(c, bflo(u[j].y), a2); a3 = fmaf(c, bfhi(u[j].y), a3);
        }
    }
    float dd = dis[node];
    uint2 u = hs[(size_t)node * 8 + lig];
    float cs = dd * dd;
    int col = sl * 32 + lig * 4;
    a0 = fmaf(cs, bflo(u.x), a0) + bias[col];
    a1 = fmaf(cs, bfhi(u.x), a1) + bias[col + 1];
    a2 = fmaf(cs, bflo(u.y), a2) + bias[col + 2];
    a3 = fmaf(cs, bfhi(u.y), a3) + bias[col + 3];
    *(float4*)(y + ((size_t)sl * n + node) * 32 + lig * 4) = make_float4(a0, a1, a2, a3);
}

// ------------------------------------------------------------ BN statistics
// y slice-major [S][n][32]; grid = (rowChunks, S)
__global__ __launch_bounds__(256) void colsum_kernel(
    const float* __restrict__ y, int n,
    float* __restrict__ sums, float* __restrict__ sumsq) {
    int sl = blockIdx.y;
    const float* ys = y + (size_t)sl * n * 32;
    int t = threadIdx.x, cg = t & 7, rt = t >> 3;
    float4 s = make_float4(0.f, 0.f, 0.f, 0.f);
    float4 q = make_float4(0.f, 0.f, 0.f, 0.f);
    for (int row = blockIdx.x * 32 + rt; row < n; row += gridDim.x * 32) {
        float4 v = *(const float4*)(ys + (size_t)row * 32 + cg * 4);
        s.x += v.x; s.y += v.y; s.z += v.z; s.w += v.w;
        q.x += v.x * v.x; q.y += v.y * v.y; q.z += v.z * v.z; q.w += v.w * v.w;
    }
    __shared__ float4 rs[32][8], rq[32][8];
    rs[rt][cg] = s; rq[rt][cg] = q;
    __syncthreads();
    for (int st = 16; st > 0; st >>= 1) {
        if (rt < st) {
            float4 o = rs[rt + st][cg], p = rq[rt + st][cg];
            rs[rt][cg].x += o.x; rs[rt][cg].y += o.y;
            rs[rt][cg].z += o.z; rs[rt][cg].w += o.w;
            rq[rt][cg].x += p.x; rq[rt][cg].y += p.y;
            rq[rt][cg].z += p.z; rq[rt][cg].w += p.w;
        }
        __syncthreads();
    }
    if (rt == 0) {
        float4 fs = rs[0][cg], fq = rq[0][cg];
        int col = sl * 32 + cg * 4;
        atomicAdd(&sums[col + 0], fs.x); atomicAdd(&sums[col + 1], fs.y);
        atomicAdd(&sums[col + 2], fs.z); atomicAdd(&sums[col + 3], fs.w);
        atomicAdd(&sumsq[col + 0], fq.x); atomicAdd(&sumsq[col + 1], fq.y);
        atomicAdd(&sumsq[col + 2], fq.z); atomicAdd(&sumsq[col + 3], fq.w);
    }
}

// finalize folds BN stats into scale/shift AND re-zeroes sums/sumsq for the
// next layer's colsum (saves 4 memset dispatches).
template <int F>
__global__ void finalize_kernel(float* __restrict__ sums,
                                float* __restrict__ sumsq,
                                const float* __restrict__ g, const float* __restrict__ be,
                                float* __restrict__ sc, float* __restrict__ sh, float n) {
    int c = threadIdx.x;
    if (c < F) {
        float m = sums[c] / n;
        float v = sumsq[c] / n - m * m;           // biased variance
        float r = rsqrtf(v + 1e-5f);
        float scale = r * g[c];
        sc[c] = scale;
        sh[c] = be[c] - m * scale;
        sums[c] = 0.f;
        sumsq[c] = 0.f;
    }
}

// ----------------------------------------------------------- final BN+ELU
// y slice-major [2][n][32] -> out row-major [n][64]
__global__ __launch_bounds__(256) void out_kernel(
    const float* __restrict__ y, const float* __restrict__ sc,
    const float* __restrict__ sh, float* __restrict__ out, int n) {
    int idx = blockIdx.x * 256 + threadIdx.x;
    if (idx >= n * 16) return;
    int node = idx >> 4, q = idx & 15;
    int sl = q >> 3, wq = (q & 7) * 4;
    int col = sl * 32 + wq;
    float4 v = *(const float4*)(y + ((size_t)sl * n + node) * 32 + wq);
    float4 s4 = *(const float4*)(sc + col);
    float4 h4 = *(const float4*)(sh + col);
    v.x = eluf(v.x * s4.x + h4.x);
    v.y = eluf(v.y * s4.y + h4.y);
    v.z = eluf(v.z * s4.z + h4.z);
    v.w = eluf(v.w * s4.w + h4.w);
    *(float4*)(out + (size_t)node * 64 + q * 4) = v;
}

// ---------------------------------------------------------------------------
extern "C" void kernel_launch(void* const* d_in, const int* in_sizes, int n_in,
                              void* d_out, int out_size, void* d_ws, size_t ws_size,
                              hipStream_t stream) {
    const float* x   = (const float*)d_in[0];
    const int*   edge = (const int*)d_in[1];
    const float* W0 = (const float*)d_in[2];
    const float* b0 = (const float*)d_in[3];
    const float* g0 = (const float*)d_in[4];
    const float* be0 = (const float*)d_in[5];
    const float* W1 = (const float*)d_in[6];
    const float* b1 = (const float*)d_in[7];
    const float* g1 = (const float*)d_in[8];
    const float* be1 = (const float*)d_in[9];
    const float* W2 = (const float*)d_in[10];
    const float* b2 = (const float*)d_in[11];
    const float* g2 = (const float*)d_in[12];
    const float* be2 = (const float*)d_in[13];

    const int n = in_sizes[0] / 128;     // 50000
    const int E = in_sizes[1] / 2;       // 1600000
    const int* esrc = edge;
    const int* edst = edge + E;

    const int NBUK = (n + 255) >> 8;               // 256-node buckets (<=256)
    const int EPC  = (E + NCH - 1) / NCH;          // edges per chunk

    char* w = (char*)d_ws;
    auto carve = [&](size_t bytes) -> void* {
        void* p = (void*)w;
        w += (bytes + 255) & ~(size_t)255;
        return p;
    };
    float*    y         = (float*)carve((size_t)n * 128 * 4);     // slice-major
    uint16_t* h         = (uint16_t*)carve((size_t)n * 128 * 2);  // slice-major
    uint32_t* csr_pk    = (uint32_t*)carve((size_t)E * 4);
    uint32_t* rec       = (uint32_t*)carve((size_t)E * 4);
    uint32_t* coarse    = (uint32_t*)carve((size_t)NBUK * NCH * 4);
    int*      beb       = (int*)carve((size_t)(NBUK + 1) * 4);
    int*      row_start = (int*)carve((size_t)(n + 1) * 4);
    float*    dis       = (float*)carve((size_t)n * 4);
    float*    sums      = (float*)carve(128 * 4);
    float*    sumsq     = (float*)carve(128 * 4);
    float*    sc        = (float*)carve(128 * 4);
    float*    sh        = (float*)carve(128 * 4);

    // ---- CSR build: counting sort + packed coef
    hist_coarse_kernel<<<NCH, 1024, 0, stream>>>(edst, coarse, E, EPC, NBUK);
    basescan_kernel<<<1, 1024, 0, stream>>>(coarse, beb, row_start, NBUK, E, n);
    partition_kernel<<<NCH, 1024, 0, stream>>>(esrc, edst, coarse, beb, rec, E, EPC, NBUK);
    fine_a_kernel<<<NBUK, 1024, 0, stream>>>(rec, beb, row_start, dis, n);
    fine_b_kernel<<<NBUK, 1024, 0, stream>>>(rec, beb, row_start, dis, csr_pk, n);

    // zero BN accumulators once; finalize re-zeroes for the next layer
    hipMemsetAsync(sums, 0, 128 * 4, stream);
    hipMemsetAsync(sumsq, 0, 128 * 4, stream);

    const uint32_t* hp = (const uint32_t*)h;
    int gGemm  = (n + 127) / 128;
    int gGrp32 = (n + 31) / 32;          // blocks of 32 nodes

    // ---- layer 0 (in = x row-major, no BN on input)
    gemm128_kernel<false, false><<<gGemm, 256, 0, stream>>>(x, W0, nullptr, nullptr, h, n);
    agg_sliced_kernel<4><<<gGrp32 * 4, 256, 0, stream>>>(hp, row_start, csr_pk, dis, b0, y, n);
    colsum_kernel<<<dim3(64, 4), 256, 0, stream>>>(y, n, sums, sumsq);
    finalize_kernel<128><<<1, 128, 0, stream>>>(sums, sumsq, g0, be0, sc, sh, (float)n);

    // ---- layer 1
    gemm128_kernel<true, true><<<gGemm, 256, 0, stream>>>(y, W1, sc, sh, h, n);
    agg_sliced_kernel<4><<<gGrp32 * 4, 256, 0, stream>>>(hp, row_start, csr_pk, dis, b1, y, n);
    colsum_kernel<<<dim3(64, 4), 256, 0, stream>>>(y, n, sums, sumsq);
    finalize_kernel<128><<<1, 128, 0, stream>>>(sums, sumsq, g1, be1, sc, sh, (float)n);

    // ---- layer 2 (F=64 -> 2 slices)
    gemm_kernel<64, true, true><<<gGemm, 512, 0, stream>>>(y, W2, sc, sh, h, n);
    agg_sliced_kernel<2><<<gGrp32 * 2, 256, 0, stream>>>(hp, row_start, csr_pk, dis, b2, y, n);
    colsum_kernel<<<dim3(64, 2), 256, 0, stream>>>(y, n, sums, sumsq);
    finalize_kernel<64><<<1, 64, 0, stream>>>(sums, sumsq, g2, be2, sc, sh, (float)n);

    // ---- final BN2 + ELU -> out
    out_kernel<<<(n * 16 + 255) / 256, 256, 0, stream>>>(y, sc, sh, (float*)d_out, n);
}